// Round 1
// baseline (2692.745 us; speedup 1.0000x reference)
//
#include <hip/hip_runtime.h>
#include <hip/hip_bf16.h>

// Network_70918499991665: implicit-map feature extractor, fwd + analytic grad.
// 12 layers; per layer: PRE[Cout,4N] = W @ XG (streams: x, gx, gy, gz), epilogue
// softplus/sigmoid. Round 0: fp32 vector-FMA core with bf16 operands (matches
// eventual MFMA numerics); layout already MFMA-ready (XG[s][n][i], padded K).

#define NPTS 4096

typedef unsigned short u16;
typedef unsigned int   u32;

__device__ __forceinline__ float bf2f(u16 h) {
  return __uint_as_float(((u32)h) << 16);
}
__device__ __forceinline__ u16 f2bf(float f) {
  u32 u = __float_as_uint(f);
  u += 0x7fff + ((u >> 16) & 1);   // RNE
  return (u16)(u >> 16);
}
__device__ __forceinline__ void unpack8(uint4 q, float* f) {
  f[0] = bf2f((u16)(q.x & 0xffff)); f[1] = bf2f((u16)(q.x >> 16));
  f[2] = bf2f((u16)(q.y & 0xffff)); f[3] = bf2f((u16)(q.y >> 16));
  f[4] = bf2f((u16)(q.z & 0xffff)); f[5] = bf2f((u16)(q.z >> 16));
  f[6] = bf2f((u16)(q.w & 0xffff)); f[7] = bf2f((u16)(q.w >> 16));
}

// softplus(100x)/100 and sigmoid(100x), numerically stable
__device__ __forceinline__ void act_sp_sg(float pre, float& sp, float& sg) {
  float z = 100.f * pre;
  float e = __expf(-fabsf(z));
  float r = 1.f / (1.f + e);
  float l = log1pf(e) * 0.01f;
  if (z >= 0.f) { sg = r;       sp = pre + l; }
  else          { sg = 1.f - r; sp = l; }
}

// ---------------- weight norm: w[o] = g[o]*v[o]/||v[o]||, store bf16, pad zeros
struct LayerDesc { const float* v; const float* g; int Cin, Kpad, Cout, Mpad, woff; };
struct AllDesc { LayerDesc d[12]; };

__global__ __launch_bounds__(256)
void wnorm_kernel(AllDesc ad, u16* __restrict__ Wall) {
  const LayerDesc L = ad.d[blockIdx.y];
  const int o = blockIdx.x;
  if (o >= L.Mpad) return;
  u16* wrow = Wall + (size_t)L.woff + (size_t)o * L.Kpad;
  const int t = threadIdx.x;
  if (o >= L.Cout) {                       // zero pad rows
    for (int i = t; i < L.Kpad; i += 256) wrow[i] = 0;
    return;
  }
  const float* vrow = L.v + (size_t)o * L.Cin;
  float ss = 0.f;
  for (int i = t; i < L.Cin; i += 256) { float x = vrow[i]; ss += x * x; }
#pragma unroll
  for (int off = 32; off > 0; off >>= 1) ss += __shfl_down(ss, off);
  __shared__ float red[4];
  if ((t & 63) == 0) red[t >> 6] = ss;
  __syncthreads();
  const float scale = L.g[o] / sqrtf(red[0] + red[1] + red[2] + red[3]);
  for (int i = t; i < L.Kpad; i += 256)
    wrow[i] = (i < L.Cin) ? f2bf(vrow[i] * scale) : (u16)0;
}

// ---------------- build x0 [n][288] bf16 (pad 0) + input_con output (f32)
__global__ __launch_bounds__(256)
void build_x0(const float* __restrict__ inp, const float* __restrict__ lat,
              u16* __restrict__ x0, float* __restrict__ con) {
  const int n = blockIdx.x;
  for (int i = threadIdx.x; i < 288; i += 256) {
    float v = (i < 3) ? inp[n * 3 + i] : ((i < 259) ? lat[i - 3] : 0.f);
    x0[(size_t)n * 288 + i] = f2bf(v);
    if (i < 259) con[(size_t)n * 259 + i] = v;
  }
}

// ---------------- fused layer GEMM: 64co x 64n x S streams, BK=32
// S==1: first layer (input grads come from W[:, :3])
template<int S>
__global__ __launch_bounds__(256)
void layer_gemm(const u16* __restrict__ W, const float* __restrict__ bias,
                const u16* __restrict__ Xin, u16* __restrict__ Xout,
                int Kpad, int Cout, int Cstr) {
  __shared__ float Ws[32][68];        // [k][co], 68 stride: 16B-aligned rows, bank-spread
  __shared__ float Xs[S][32][68];     // [s][k][n]
  const int t  = threadIdx.x;
  const int tx = t & 15, ty = t >> 4;
  const int n0 = blockIdx.x * 64;
  const int m0 = blockIdx.y * 64;

  float acc[S][4][4];
#pragma unroll
  for (int s = 0; s < S; ++s)
#pragma unroll
    for (int i = 0; i < 4; ++i)
#pragma unroll
      for (int j = 0; j < 4; ++j) acc[s][i][j] = 0.f;

  const int ksteps = Kpad >> 5;
  const int wr = t >> 2, wc = t & 3;     // W staging: row 0..63, 8-elem chunk 0..3
  const int xs = t >> 6, xi = t & 63;    // X staging: wave = stream
  const int xc = xi & 3, xr = xi >> 2;   // chunk, row-base

  for (int ks = 0; ks < ksteps; ++ks) {
    const int k0 = ks << 5;
    {   // stage W tile [64 co][32 k] -> Ws[k][co] (coalesced 64B/row)
      uint4 q = *reinterpret_cast<const uint4*>(
          W + (size_t)(m0 + wr) * Kpad + k0 + wc * 8);
      float f[8]; unpack8(q, f);
      const int cc = wc * 8;
#pragma unroll
      for (int j = 0; j < 8; ++j) Ws[cc + j][wr] = f[j];
    }
    if (xs < S) {   // stage X tiles [64 n][32 k] -> Xs[s][k][n]
#pragma unroll
      for (int rr = 0; rr < 4; ++rr) {
        const int n = xr + rr * 16;
        uint4 q = *reinterpret_cast<const uint4*>(
            Xin + ((size_t)xs * NPTS + n0 + n) * Kpad + k0 + xc * 8);
        float f[8]; unpack8(q, f);
        const int cc = xc * 8;
#pragma unroll
        for (int j = 0; j < 8; ++j) Xs[xs][cc + j][n] = f[j];
      }
    }
    __syncthreads();
#pragma unroll 4
    for (int kk = 0; kk < 32; ++kk) {
      const float4 wv = *reinterpret_cast<const float4*>(&Ws[kk][ty * 4]);
#pragma unroll
      for (int s = 0; s < S; ++s) {
        const float4 xv = *reinterpret_cast<const float4*>(&Xs[s][kk][tx * 4]);
        acc[s][0][0] += wv.x * xv.x; acc[s][0][1] += wv.x * xv.y;
        acc[s][0][2] += wv.x * xv.z; acc[s][0][3] += wv.x * xv.w;
        acc[s][1][0] += wv.y * xv.x; acc[s][1][1] += wv.y * xv.y;
        acc[s][1][2] += wv.y * xv.z; acc[s][1][3] += wv.y * xv.w;
        acc[s][2][0] += wv.z * xv.x; acc[s][2][1] += wv.z * xv.y;
        acc[s][2][2] += wv.z * xv.z; acc[s][2][3] += wv.z * xv.w;
        acc[s][3][0] += wv.w * xv.x; acc[s][3][1] += wv.w * xv.y;
        acc[s][3][2] += wv.w * xv.z; acc[s][3][3] += wv.w * xv.w;
      }
    }
    __syncthreads();
  }

  // epilogue: bias + softplus/sigmoid, write 4 streams bf16 [s][n][co]
#pragma unroll
  for (int j = 0; j < 4; ++j) {
    const int n = n0 + tx * 4 + j;
    u16 outv[4][4];
#pragma unroll
    for (int i = 0; i < 4; ++i) {
      const int co = m0 + ty * 4 + i;
      float sp = 0.f, o1 = 0.f, o2 = 0.f, o3 = 0.f;
      if (co < Cout) {
        const float pre = acc[0][i][j] + bias[co];
        float sg; act_sp_sg(pre, sp, sg);
        if constexpr (S == 1) {
          o1 = sg * bf2f(W[(size_t)co * Kpad + 0]);
          o2 = sg * bf2f(W[(size_t)co * Kpad + 1]);
          o3 = sg * bf2f(W[(size_t)co * Kpad + 2]);
        } else {
          o1 = sg * acc[1][i][j];
          o2 = sg * acc[2][i][j];
          o3 = sg * acc[3][i][j];
        }
      }
      outv[0][i] = f2bf(sp); outv[1][i] = f2bf(o1);
      outv[2][i] = f2bf(o2); outv[3][i] = f2bf(o3);
    }
    if (m0 + ty * 4 < Cstr) {
#pragma unroll
      for (int s = 0; s < 4; ++s) {
        *reinterpret_cast<ushort4*>(
            &Xout[((size_t)s * NPTS + n) * Cstr + m0 + ty * 4]) =
            make_ushort4(outv[s][0], outv[s][1], outv[s][2], outv[s][3]);
      }
    }
  }
}

// ---------------- final 1-channel layer: out + out_grad
__global__ __launch_bounds__(256)
void final_c10(const u16* __restrict__ W10, const float* __restrict__ b10,
               const u16* __restrict__ Xin, float* __restrict__ out,
               float* __restrict__ outg) {
  const int lane = threadIdx.x & 63;
  const int n = blockIdx.x * 4 + (threadIdx.x >> 6);
  float a0 = 0, a1 = 0, a2 = 0, a3 = 0;
  for (int i = lane; i < 896; i += 64) {
    const float w = bf2f(W10[i]);
    a0 += w * bf2f(Xin[((size_t)0 * NPTS + n) * 896 + i]);
    a1 += w * bf2f(Xin[((size_t)1 * NPTS + n) * 896 + i]);
    a2 += w * bf2f(Xin[((size_t)2 * NPTS + n) * 896 + i]);
    a3 += w * bf2f(Xin[((size_t)3 * NPTS + n) * 896 + i]);
  }
#pragma unroll
  for (int off = 32; off > 0; off >>= 1) {
    a0 += __shfl_xor(a0, off); a1 += __shfl_xor(a1, off);
    a2 += __shfl_xor(a2, off); a3 += __shfl_xor(a3, off);
  }
  if (lane == 0) {
    out[n] = a0 + b10[0];
    outg[n * 3 + 0] = a1; outg[n * 3 + 1] = a2; outg[n * 3 + 2] = a3;
  }
}

extern "C" void kernel_launch(void* const* d_in, const int* in_sizes, int n_in,
                              void* d_out, int out_size, void* d_ws, size_t ws_size,
                              hipStream_t stream) {
  // layer tables: Cin, padded K (mult of 32), Cout, padded M (mult of 64; c10=1)
  static const int CIN [12] = {259,515,512,512,576,576,768,768,768,960,960,896};
  static const int KPAD[12] = {288,544,512,512,576,576,768,768,768,960,960,896};
  static const int COUT[12] = {515,512,512,576,576,768,768,768,960,960,896,1};
  static const int MPAD[12] = {576,512,512,576,576,768,768,768,960,960,896,1};

  size_t woff[13]; woff[0] = 0;
  for (int l = 0; l < 12; ++l) woff[l + 1] = woff[l] + (size_t)MPAD[l] * KPAD[l];

  char* ws = (char*)d_ws;
  u16* Wall = (u16*)ws;
  size_t off = (woff[12] * 2 + 255) & ~(size_t)255;
  u16* x0  = (u16*)(ws + off); off += (size_t)NPTS * 288 * 2;
  u16* XGA = (u16*)(ws + off); off += (size_t)4 * NPTS * 960 * 2;
  u16* XGB = (u16*)(ws + off);
  // total ws use ~76.3 MB

  float* out_sdf  = (float*)d_out;           // [4096]
  float* out_grad = out_sdf + NPTS;          // [4096][3]
  float* out_con  = out_sdf + NPTS + NPTS*3; // [4096][259]

  build_x0<<<dim3(NPTS), dim3(256), 0, stream>>>(
      (const float*)d_in[0], (const float*)d_in[1], x0, out_con);

  AllDesc ad;
  for (int l = 0; l < 12; ++l) {
    ad.d[l].v = (const float*)d_in[2 + 3 * l];
    ad.d[l].g = (const float*)d_in[3 + 3 * l];
    ad.d[l].Cin = CIN[l]; ad.d[l].Kpad = KPAD[l];
    ad.d[l].Cout = COUT[l]; ad.d[l].Mpad = MPAD[l];
    ad.d[l].woff = (int)woff[l];
  }
  wnorm_kernel<<<dim3(960, 12), dim3(256), 0, stream>>>(ad, Wall);

  // layer 0 (first): x0 -> XGA (stride 544)
  layer_gemm<1><<<dim3(64, MPAD[0] / 64), dim3(256), 0, stream>>>(
      Wall + woff[0], (const float*)d_in[4], x0, XGA, KPAD[0], COUT[0], KPAD[1]);

  // layers 1..10: ping-pong
  u16* bufs[2] = {XGA, XGB};
  for (int l = 1; l <= 10; ++l) {
    u16* Xi = bufs[(l + 1) & 1];
    u16* Xo = bufs[l & 1];
    layer_gemm<4><<<dim3(64, MPAD[l] / 64), dim3(256), 0, stream>>>(
        Wall + woff[l], (const float*)d_in[4 + 3 * l], Xi, Xo,
        KPAD[l], COUT[l], KPAD[l + 1]);
  }

  // final: layer 10 wrote XGA (stride 896)
  final_c10<<<dim3(NPTS / 4), dim3(256), 0, stream>>>(
      Wall + woff[11], (const float*)d_in[37], XGA, out_sdf, out_grad);
}

// Round 2
// 1093.026 us; speedup vs baseline: 2.4636x; 2.4636x over previous
//
#include <hip/hip_runtime.h>
#include <hip/hip_bf16.h>

// Network_70918499991665: 12-layer implicit-map extractor, fwd + analytic grad.
// Round 1: MFMA core (16x16x32 bf16), 128x128xBK64 tiles, 4 waves.
// Mid-layer tiles: rows = 4 streams x 32 points -> in-block sigmoid coupling via LDS.

#define NPTS 4096

typedef unsigned short u16;
typedef unsigned int   u32;
typedef __attribute__((ext_vector_type(8))) __bf16 bf16x8;
typedef __attribute__((ext_vector_type(4))) float  f32x4;

__device__ __forceinline__ float bf2f(u16 h) {
  return __uint_as_float(((u32)h) << 16);
}
__device__ __forceinline__ u16 f2bf(float f) {
  u32 u = __float_as_uint(f);
  u += 0x7fff + ((u >> 16) & 1);   // RNE
  return (u16)(u >> 16);
}

// softplus(100x)/100 and sigmoid(100x), numerically stable
__device__ __forceinline__ void act_sp_sg(float pre, float& sp, float& sg) {
  float z = 100.f * pre;
  float e = __expf(-fabsf(z));
  float r = 1.f / (1.f + e);
  float l = log1pf(e) * 0.01f;
  if (z >= 0.f) { sg = r;       sp = pre + l; }
  else          { sg = 1.f - r; sp = l; }
}

// ---------------- weight norm: w[o] = g[o]*v[o]/||v[o]||, store bf16, pad zeros
struct LayerDesc { const float* v; const float* g; int Cin, Kpad, Cout, Mpad, woff; };
struct AllDesc { LayerDesc d[12]; };

__global__ __launch_bounds__(256)
void wnorm_kernel(AllDesc ad, u16* __restrict__ Wall) {
  const LayerDesc L = ad.d[blockIdx.y];
  const int o = blockIdx.x;
  if (o >= L.Mpad) return;
  u16* wrow = Wall + (size_t)L.woff + (size_t)o * L.Kpad;
  const int t = threadIdx.x;
  if (o >= L.Cout) {                       // zero pad rows
    for (int i = t; i < L.Kpad; i += 256) wrow[i] = 0;
    return;
  }
  const float* vrow = L.v + (size_t)o * L.Cin;
  float ss = 0.f;
  for (int i = t; i < L.Cin; i += 256) { float x = vrow[i]; ss += x * x; }
#pragma unroll
  for (int off = 32; off > 0; off >>= 1) ss += __shfl_down(ss, off);
  __shared__ float red[4];
  if ((t & 63) == 0) red[t >> 6] = ss;
  __syncthreads();
  const float scale = L.g[o] / sqrtf(red[0] + red[1] + red[2] + red[3]);
  for (int i = t; i < L.Kpad; i += 256)
    wrow[i] = (i < L.Cin) ? f2bf(vrow[i] * scale) : (u16)0;
}

// ---------------- build x0 [n][320] bf16 (pad 0) + input_con output (f32)
__global__ __launch_bounds__(256)
void build_x0(const float* __restrict__ inp, const float* __restrict__ lat,
              u16* __restrict__ x0, float* __restrict__ con) {
  const int n = blockIdx.x;
  for (int i = threadIdx.x; i < 320; i += 256) {
    float v = (i < 3) ? inp[n * 3 + i] : ((i < 259) ? lat[i - 3] : 0.f);
    x0[(size_t)n * 320 + i] = f2bf(v);
    if (i < 259) con[(size_t)n * 259 + i] = v;
  }
}

// ---------------- fused MFMA layer
// FIRST: tile rows = 128 points (grads from W[:, :3]).
// else : tile rows = 4 streams x 32 points (sigmoid coupling via LDS).
template<bool FIRST>
__global__ __launch_bounds__(256)
void layer_mfma(const u16* __restrict__ W, const float* __restrict__ bias,
                const u16* __restrict__ Xin, u16* __restrict__ Xout,
                int Kpad, int Cout, int Cstr) {
  __shared__ __align__(16) u16 As[128 * 72];   // [row][k], stride 72 (pad)
  __shared__ __align__(16) u16 Bs[128 * 72];   // [co ][k]
  const int t = threadIdx.x;
  const int wid = t >> 6, lane = t & 63;
  const int wr = wid >> 1, wc = wid & 1;
  const int lcol = lane & 15;
  const int lrow4 = (lane >> 4) * 4;
  const int kg = (lane >> 4) * 8;
  const int n0 = blockIdx.x * (FIRST ? 128 : 32);
  const int m0 = blockIdx.y * 128;

  f32x4 acc[4][4];
#pragma unroll
  for (int m = 0; m < 4; ++m)
#pragma unroll
    for (int n = 0; n < 4; ++n) acc[m][n] = (f32x4){0.f, 0.f, 0.f, 0.f};

  uint4 ra[4], rb[4];
  auto stage_load = [&](int k0) {
#pragma unroll
    for (int i = 0; i < 4; ++i) {
      const int q = i * 256 + t, row = q >> 3, kc = q & 7;
      const size_t arow = FIRST ? (size_t)(n0 + row)
                                : ((size_t)(row >> 5) * NPTS + (size_t)(n0 + (row & 31)));
      ra[i] = *reinterpret_cast<const uint4*>(Xin + arow * (size_t)Kpad + k0 + kc * 8);
      rb[i] = *reinterpret_cast<const uint4*>(W + (size_t)(m0 + row) * Kpad + k0 + kc * 8);
    }
  };

  stage_load(0);
  const int ksteps = Kpad >> 6;
  for (int ks = 0; ks < ksteps; ++ks) {
    __syncthreads();
#pragma unroll
    for (int i = 0; i < 4; ++i) {
      const int q = i * 256 + t, row = q >> 3, kc = q & 7;
      *reinterpret_cast<uint4*>(&As[row * 72 + kc * 8]) = ra[i];
      *reinterpret_cast<uint4*>(&Bs[row * 72 + kc * 8]) = rb[i];
    }
    __syncthreads();
    if (ks + 1 < ksteps) stage_load((ks + 1) << 6);
#pragma unroll
    for (int kk = 0; kk < 2; ++kk) {
      bf16x8 af[4], bfr[4];
#pragma unroll
      for (int m = 0; m < 4; ++m)
        af[m] = *reinterpret_cast<const bf16x8*>(
            &As[(wr * 64 + m * 16 + lcol) * 72 + kk * 32 + kg]);
#pragma unroll
      for (int n = 0; n < 4; ++n)
        bfr[n] = *reinterpret_cast<const bf16x8*>(
            &Bs[(wc * 64 + n * 16 + lcol) * 72 + kk * 32 + kg]);
#pragma unroll
      for (int m = 0; m < 4; ++m)
#pragma unroll
        for (int n = 0; n < 4; ++n)
          acc[m][n] = __builtin_amdgcn_mfma_f32_16x16x32_bf16(af[m], bfr[n], acc[m][n], 0, 0, 0);
    }
  }
  __syncthreads();   // LDS free before sg-buffer reuse

  if constexpr (!FIRST) {
    float* sgL = reinterpret_cast<float*>(As);   // [32][132] f32, reuses A-tile
    if (wr == 0) {     // phase 1: stream-0 rows (0..31) -> sg to LDS, sp into acc
#pragma unroll
      for (int m = 0; m < 2; ++m)
#pragma unroll
        for (int n = 0; n < 4; ++n) {
          const int colL = wc * 64 + n * 16 + lcol;
          const int col = m0 + colL;
          const float bcol = (col < Cout) ? bias[col] : 0.f;
#pragma unroll
          for (int i = 0; i < 4; ++i) {
            const int p = m * 16 + lrow4 + i;
            float sp = 0.f, sg = 0.f;
            if (col < Cout) act_sp_sg(acc[m][n][i] + bcol, sp, sg);
            sgL[p * 132 + colL] = sg;
            acc[m][n][i] = sp;
          }
        }
    }
    __syncthreads();
#pragma unroll
    for (int m = 0; m < 4; ++m)
#pragma unroll
      for (int n = 0; n < 4; ++n) {
        const int colL = wc * 64 + n * 16 + lcol;
        const int col = m0 + colL;
        if (col >= Cstr) continue;
#pragma unroll
        for (int i = 0; i < 4; ++i) {
          const int row = wr * 64 + m * 16 + lrow4 + i;
          const int s = row >> 5, p = row & 31;
          const float v = (s == 0) ? acc[m][n][i]
                                   : sgL[p * 132 + colL] * acc[m][n][i];
          Xout[((size_t)s * NPTS + n0 + p) * Cstr + col] = f2bf(v);
        }
      }
  } else {
#pragma unroll
    for (int m = 0; m < 4; ++m)
#pragma unroll
      for (int n = 0; n < 4; ++n) {
        const int col = m0 + wc * 64 + n * 16 + lcol;
        if (col >= Cstr) continue;
        float bcol = 0.f, w0 = 0.f, w1 = 0.f, w2 = 0.f;
        if (col < Cout) {
          bcol = bias[col];
          w0 = bf2f(W[(size_t)col * Kpad + 0]);
          w1 = bf2f(W[(size_t)col * Kpad + 1]);
          w2 = bf2f(W[(size_t)col * Kpad + 2]);
        }
#pragma unroll
        for (int i = 0; i < 4; ++i) {
          const int p = wr * 64 + m * 16 + lrow4 + i;
          float sp = 0.f, sg = 0.f;
          if (col < Cout) act_sp_sg(acc[m][n][i] + bcol, sp, sg);
          const size_t base = (size_t)(n0 + p) * Cstr + col;
          Xout[base] = f2bf(sp);
          Xout[(size_t)1 * NPTS * Cstr + base] = f2bf(sg * w0);
          Xout[(size_t)2 * NPTS * Cstr + base] = f2bf(sg * w1);
          Xout[(size_t)3 * NPTS * Cstr + base] = f2bf(sg * w2);
        }
      }
  }
}

// ---------------- final 1-channel layer: out + out_grad
__global__ __launch_bounds__(256)
void final_c10(const u16* __restrict__ W10, const float* __restrict__ b10,
               const u16* __restrict__ Xin, float* __restrict__ out,
               float* __restrict__ outg) {
  const int lane = threadIdx.x & 63;
  const int n = blockIdx.x * 4 + (threadIdx.x >> 6);
  float a0 = 0, a1 = 0, a2 = 0, a3 = 0;
  for (int i = lane; i < 896; i += 64) {
    const float w = bf2f(W10[i]);
    a0 += w * bf2f(Xin[((size_t)0 * NPTS + n) * 896 + i]);
    a1 += w * bf2f(Xin[((size_t)1 * NPTS + n) * 896 + i]);
    a2 += w * bf2f(Xin[((size_t)2 * NPTS + n) * 896 + i]);
    a3 += w * bf2f(Xin[((size_t)3 * NPTS + n) * 896 + i]);
  }
#pragma unroll
  for (int off = 32; off > 0; off >>= 1) {
    a0 += __shfl_xor(a0, off); a1 += __shfl_xor(a1, off);
    a2 += __shfl_xor(a2, off); a3 += __shfl_xor(a3, off);
  }
  if (lane == 0) {
    out[n] = a0 + b10[0];
    outg[n * 3 + 0] = a1; outg[n * 3 + 1] = a2; outg[n * 3 + 2] = a3;
  }
}

extern "C" void kernel_launch(void* const* d_in, const int* in_sizes, int n_in,
                              void* d_out, int out_size, void* d_ws, size_t ws_size,
                              hipStream_t stream) {
  // K padded to 64-mult; Cout padded to 128-mult (MPAD).
  static const int CIN [12] = {259,515,512,512,576,576,768,768,768,960,960,896};
  static const int KPAD[12] = {320,576,512,512,576,576,768,768,768,960,960,896};
  static const int COUT[12] = {515,512,512,576,576,768,768,768,960,960,896,1};
  static const int MPAD[12] = {640,512,512,640,640,768,768,768,1024,1024,896,1};

  size_t woff[13]; woff[0] = 0;
  for (int l = 0; l < 12; ++l) woff[l + 1] = woff[l] + (size_t)MPAD[l] * KPAD[l];

  char* ws = (char*)d_ws;
  u16* Wall = (u16*)ws;
  size_t off = (woff[12] * 2 + 255) & ~(size_t)255;
  u16* x0  = (u16*)(ws + off); off += (size_t)NPTS * 320 * 2;
  u16* XGA = (u16*)(ws + off); off += (size_t)4 * NPTS * 960 * 2;
  u16* XGB = (u16*)(ws + off);
  // total ws use ~77 MB

  float* out_sdf  = (float*)d_out;           // [4096]
  float* out_grad = out_sdf + NPTS;          // [4096][3]
  float* out_con  = out_sdf + NPTS + NPTS*3; // [4096][259]

  build_x0<<<dim3(NPTS), dim3(256), 0, stream>>>(
      (const float*)d_in[0], (const float*)d_in[1], x0, out_con);

  AllDesc ad;
  for (int l = 0; l < 12; ++l) {
    ad.d[l].v = (const float*)d_in[2 + 3 * l];
    ad.d[l].g = (const float*)d_in[3 + 3 * l];
    ad.d[l].Cin = CIN[l]; ad.d[l].Kpad = KPAD[l];
    ad.d[l].Cout = COUT[l]; ad.d[l].Mpad = MPAD[l];
    ad.d[l].woff = (int)woff[l];
  }
  wnorm_kernel<<<dim3(1024, 12), dim3(256), 0, stream>>>(ad, Wall);

  // layer 0 (first): x0 -> XGA (out stride = KPAD[1])
  layer_mfma<true><<<dim3(NPTS / 128, MPAD[0] / 128), dim3(256), 0, stream>>>(
      Wall + woff[0], (const float*)d_in[4], x0, XGA, KPAD[0], COUT[0], KPAD[1]);

  // layers 1..10: ping-pong; tile rows = 4 streams x 32 points
  u16* bufs[2] = {XGA, XGB};
  for (int l = 1; l <= 10; ++l) {
    u16* Xi = bufs[(l + 1) & 1];
    u16* Xo = bufs[l & 1];
    layer_mfma<false><<<dim3(NPTS / 32, MPAD[l] / 128), dim3(256), 0, stream>>>(
        Wall + woff[l], (const float*)d_in[4 + 3 * l], Xi, Xo,
        KPAD[l], COUT[l], KPAD[l + 1]);
  }

  // final: layer 10 wrote XGA (stride 896)
  final_c10<<<dim3(NPTS / 4), dim3(256), 0, stream>>>(
      Wall + woff[11], (const float*)d_in[37], XGA, out_sdf, out_grad);
}

// Round 3
// 1059.351 us; speedup vs baseline: 2.5419x; 1.0318x over previous
//
#include <hip/hip_runtime.h>
#include <hip/hip_bf16.h>

// Network_70918499991665: 12-layer implicit-map extractor, fwd + analytic grad.
// Round 2: fix 12x write amplification (scattered u16 stores -> LDS-staged uint4
// stores), XCD-aware bijective block swizzle (m-major chunks).

#define NPTS 4096

typedef unsigned short u16;
typedef unsigned int   u32;
typedef __attribute__((ext_vector_type(8))) __bf16 bf16x8;
typedef __attribute__((ext_vector_type(4))) float  f32x4;

__device__ __forceinline__ float bf2f(u16 h) {
  return __uint_as_float(((u32)h) << 16);
}
__device__ __forceinline__ u16 f2bf(float f) {
  u32 u = __float_as_uint(f);
  u += 0x7fff + ((u >> 16) & 1);   // RNE
  return (u16)(u >> 16);
}

// softplus(100x)/100 and sigmoid(100x), numerically stable
__device__ __forceinline__ void act_sp_sg(float pre, float& sp, float& sg) {
  float z = 100.f * pre;
  float e = __expf(-fabsf(z));
  float r = 1.f / (1.f + e);
  float l = log1pf(e) * 0.01f;
  if (z >= 0.f) { sg = r;       sp = pre + l; }
  else          { sg = 1.f - r; sp = l; }
}

// ---------------- weight norm: w[o] = g[o]*v[o]/||v[o]||, store bf16, pad zeros
struct LayerDesc { const float* v; const float* g; int Cin, Kpad, Cout, Mpad, woff; };
struct AllDesc { LayerDesc d[12]; };

__global__ __launch_bounds__(256)
void wnorm_kernel(AllDesc ad, u16* __restrict__ Wall) {
  const LayerDesc L = ad.d[blockIdx.y];
  const int o = blockIdx.x;
  if (o >= L.Mpad) return;
  u16* wrow = Wall + (size_t)L.woff + (size_t)o * L.Kpad;
  const int t = threadIdx.x;
  if (o >= L.Cout) {                       // zero pad rows
    for (int i = t; i < L.Kpad; i += 256) wrow[i] = 0;
    return;
  }
  const float* vrow = L.v + (size_t)o * L.Cin;
  float ss = 0.f;
  for (int i = t; i < L.Cin; i += 256) { float x = vrow[i]; ss += x * x; }
#pragma unroll
  for (int off = 32; off > 0; off >>= 1) ss += __shfl_down(ss, off);
  __shared__ float red[4];
  if ((t & 63) == 0) red[t >> 6] = ss;
  __syncthreads();
  const float scale = L.g[o] / sqrtf(red[0] + red[1] + red[2] + red[3]);
  for (int i = t; i < L.Kpad; i += 256)
    wrow[i] = (i < L.Cin) ? f2bf(vrow[i] * scale) : (u16)0;
}

// ---------------- build x0 [n][320] bf16 (pad 0) + input_con output (f32)
__global__ __launch_bounds__(256)
void build_x0(const float* __restrict__ inp, const float* __restrict__ lat,
              u16* __restrict__ x0, float* __restrict__ con) {
  const int n = blockIdx.x;
  for (int i = threadIdx.x; i < 320; i += 256) {
    float v = (i < 3) ? inp[n * 3 + i] : ((i < 259) ? lat[i - 3] : 0.f);
    x0[(size_t)n * 320 + i] = f2bf(v);
    if (i < 259) con[(size_t)n * 259 + i] = v;
  }
}

// bijective XCD swizzle (nb % 8 == 0 guaranteed by grid construction),
// m-major within each XCD chunk: consecutive wg share the same n-tile.
__device__ __forceinline__ void xcd_decode(int nb, int ny, int& bx, int& by) {
  const int q = nb >> 3;
  const int wg = (blockIdx.x & 7) * q + (blockIdx.x >> 3);
  bx = wg / ny;
  by = wg - bx * ny;
}

// ---------------- fused MFMA layer
// FIRST: tile rows = 128 points (grads from W[:, :3]).
// else : tile rows = 4 streams x 32 points (sigmoid coupling via LDS).
template<bool FIRST>
__global__ __launch_bounds__(256)
void layer_mfma(const u16* __restrict__ W, const float* __restrict__ bias,
                const u16* __restrict__ Xin, u16* __restrict__ Xout,
                int Kpad, int Cout, int Cstr, int ny) {
  __shared__ __align__(16) u16 smem[18432];    // 36,864 B
  u16* As = smem;                              // [128][72]
  u16* Bs = smem + 9216;                       // [128][72]
  const int t = threadIdx.x;
  const int wid = t >> 6, lane = t & 63;
  const int wr = wid >> 1, wc = wid & 1;
  const int lcol = lane & 15;
  const int lrow4 = (lane >> 4) * 4;
  const int kg = (lane >> 4) * 8;

  int bx, by;
  xcd_decode(gridDim.x, ny, bx, by);
  const int n0 = bx * (FIRST ? 128 : 32);
  const int m0 = by * 128;

  f32x4 acc[4][4];
#pragma unroll
  for (int m = 0; m < 4; ++m)
#pragma unroll
    for (int n = 0; n < 4; ++n) acc[m][n] = (f32x4){0.f, 0.f, 0.f, 0.f};

  uint4 ra[4], rb[4];
  auto stage_load = [&](int k0) {
#pragma unroll
    for (int i = 0; i < 4; ++i) {
      const int q = i * 256 + t, row = q >> 3, kc = q & 7;
      const size_t arow = FIRST ? (size_t)(n0 + row)
                                : ((size_t)(row >> 5) * NPTS + (size_t)(n0 + (row & 31)));
      ra[i] = *reinterpret_cast<const uint4*>(Xin + arow * (size_t)Kpad + k0 + kc * 8);
      rb[i] = *reinterpret_cast<const uint4*>(W + (size_t)(m0 + row) * Kpad + k0 + kc * 8);
    }
  };

  stage_load(0);
  const int ksteps = Kpad >> 6;
  for (int ks = 0; ks < ksteps; ++ks) {
    __syncthreads();
#pragma unroll
    for (int i = 0; i < 4; ++i) {
      const int q = i * 256 + t, row = q >> 3, kc = q & 7;
      *reinterpret_cast<uint4*>(&As[row * 72 + kc * 8]) = ra[i];
      *reinterpret_cast<uint4*>(&Bs[row * 72 + kc * 8]) = rb[i];
    }
    __syncthreads();
    if (ks + 1 < ksteps) stage_load((ks + 1) << 6);
#pragma unroll
    for (int kk = 0; kk < 2; ++kk) {
      bf16x8 af[4], bfr[4];
#pragma unroll
      for (int m = 0; m < 4; ++m)
        af[m] = *reinterpret_cast<const bf16x8*>(
            &As[(wr * 64 + m * 16 + lcol) * 72 + kk * 32 + kg]);
#pragma unroll
      for (int n = 0; n < 4; ++n)
        bfr[n] = *reinterpret_cast<const bf16x8*>(
            &Bs[(wc * 64 + n * 16 + lcol) * 72 + kk * 32 + kg]);
#pragma unroll
      for (int m = 0; m < 4; ++m)
#pragma unroll
        for (int n = 0; n < 4; ++n)
          acc[m][n] = __builtin_amdgcn_mfma_f32_16x16x32_bf16(af[m], bfr[n], acc[m][n], 0, 0, 0);
    }
  }
  __syncthreads();   // MFMA LDS reads done; smem free for epilogue reuse

  if constexpr (!FIRST) {
    u16* tile = smem;                                     // [64][144] u16
    float* sgL = reinterpret_cast<float*>(smem + 9216);   // [32][133] f32

    if (wr == 0) {     // stream-0 rows (0..31): sg -> LDS, acc -> softplus
#pragma unroll
      for (int m = 0; m < 2; ++m)
#pragma unroll
        for (int n = 0; n < 4; ++n) {
          const int colL = wc * 64 + n * 16 + lcol;
          const int col = m0 + colL;
          const float bcol = (col < Cout) ? bias[col] : 0.f;
#pragma unroll
          for (int i = 0; i < 4; ++i) {
            const int p = m * 16 + lrow4 + i;
            float sp = 0.f, sg = 0.f;
            if (col < Cout) act_sp_sg(acc[m][n][i] + bcol, sp, sg);
            sgL[p * 133 + colL] = sg;
            acc[m][n][i] = sp;
          }
        }
    }
    __syncthreads();

    auto store_half = [&](int sbase) {
#pragma unroll
      for (int j = 0; j < 4; ++j) {
        const int c = j * 256 + t;
        const int row = c >> 4, colc = c & 15;
        const int colg = m0 + colc * 8;
        if (colg < Cstr) {
          const int s = sbase + (row >> 5), p = row & 31;
          *reinterpret_cast<uint4*>(
              &Xout[((size_t)s * NPTS + n0 + p) * Cstr + colg]) =
              *reinterpret_cast<const uint4*>(&tile[row * 144 + colc * 8]);
        }
      }
    };

    // half A: rows 0..63 = streams 0,1 (owned by wr==0 waves)
    if (wr == 0) {
#pragma unroll
      for (int m = 0; m < 4; ++m)
#pragma unroll
        for (int n = 0; n < 4; ++n) {
          const int colL = wc * 64 + n * 16 + lcol;
#pragma unroll
          for (int i = 0; i < 4; ++i) {
            const int row = m * 16 + lrow4 + i;   // 0..63
            const float v = (row < 32) ? acc[m][n][i]
                                       : sgL[(row & 31) * 133 + colL] * acc[m][n][i];
            tile[row * 144 + colL] = f2bf(v);
          }
        }
    }
    __syncthreads();
    store_half(0);
    __syncthreads();
    // half B: rows 64..127 = streams 2,3 (owned by wr==1 waves)
    if (wr == 1) {
#pragma unroll
      for (int m = 0; m < 4; ++m)
#pragma unroll
        for (int n = 0; n < 4; ++n) {
          const int colL = wc * 64 + n * 16 + lcol;
#pragma unroll
          for (int i = 0; i < 4; ++i) {
            const int row = m * 16 + lrow4 + i;   // tile row 0..63
            const float v = sgL[(row & 31) * 133 + colL] * acc[m][n][i];
            tile[row * 144 + colL] = f2bf(v);
          }
        }
    }
    __syncthreads();
    store_half(2);
  } else {
    u16* tile = smem;                                     // [128][144] u16
    float w0r[4], w1r[4], w2r[4], bcolr[4];
#pragma unroll
    for (int n = 0; n < 4; ++n) {
      const int col = m0 + wc * 64 + n * 16 + lcol;
      float b = 0.f, w0 = 0.f, w1 = 0.f, w2 = 0.f;
      if (col < Cout) {
        b  = bias[col];
        w0 = bf2f(W[(size_t)col * Kpad + 0]);
        w1 = bf2f(W[(size_t)col * Kpad + 1]);
        w2 = bf2f(W[(size_t)col * Kpad + 2]);
      }
      bcolr[n] = b; w0r[n] = w0; w1r[n] = w1; w2r[n] = w2;
    }
#pragma unroll
    for (int s = 0; s < 4; ++s) {
      if (s > 0) __syncthreads();
      const int col_ok_base = m0 + wc * 64;
#pragma unroll
      for (int m = 0; m < 4; ++m)
#pragma unroll
        for (int n = 0; n < 4; ++n) {
          const int colL = wc * 64 + n * 16 + lcol;
          const bool ok = (col_ok_base + n * 16 + lcol) < Cout;
#pragma unroll
          for (int i = 0; i < 4; ++i) {
            const int row = wr * 64 + m * 16 + lrow4 + i;
            float v = 0.f;
            if (ok) {
              float sp, sg;
              act_sp_sg(acc[m][n][i] + bcolr[n], sp, sg);
              v = (s == 0) ? sp
                : (s == 1) ? sg * w0r[n]
                : (s == 2) ? sg * w1r[n]
                           : sg * w2r[n];
            }
            tile[row * 144 + colL] = f2bf(v);
          }
        }
      __syncthreads();
#pragma unroll
      for (int j = 0; j < 8; ++j) {
        const int c = j * 256 + t;
        const int row = c >> 4, colc = c & 15;
        const int colg = m0 + colc * 8;
        if (colg < Cstr) {
          *reinterpret_cast<uint4*>(
              &Xout[((size_t)s * NPTS + n0 + row) * Cstr + colg]) =
              *reinterpret_cast<const uint4*>(&tile[row * 144 + colc * 8]);
        }
      }
    }
  }
}

// ---------------- final 1-channel layer: out + out_grad
__global__ __launch_bounds__(256)
void final_c10(const u16* __restrict__ W10, const float* __restrict__ b10,
               const u16* __restrict__ Xin, float* __restrict__ out,
               float* __restrict__ outg) {
  const int lane = threadIdx.x & 63;
  const int n = blockIdx.x * 4 + (threadIdx.x >> 6);
  float a0 = 0, a1 = 0, a2 = 0, a3 = 0;
  for (int i = lane; i < 896; i += 64) {
    const float w = bf2f(W10[i]);
    a0 += w * bf2f(Xin[((size_t)0 * NPTS + n) * 896 + i]);
    a1 += w * bf2f(Xin[((size_t)1 * NPTS + n) * 896 + i]);
    a2 += w * bf2f(Xin[((size_t)2 * NPTS + n) * 896 + i]);
    a3 += w * bf2f(Xin[((size_t)3 * NPTS + n) * 896 + i]);
  }
#pragma unroll
  for (int off = 32; off > 0; off >>= 1) {
    a0 += __shfl_xor(a0, off); a1 += __shfl_xor(a1, off);
    a2 += __shfl_xor(a2, off); a3 += __shfl_xor(a3, off);
  }
  if (lane == 0) {
    out[n] = a0 + b10[0];
    outg[n * 3 + 0] = a1; outg[n * 3 + 1] = a2; outg[n * 3 + 2] = a3;
  }
}

extern "C" void kernel_launch(void* const* d_in, const int* in_sizes, int n_in,
                              void* d_out, int out_size, void* d_ws, size_t ws_size,
                              hipStream_t stream) {
  // K padded to 64-mult; Cout padded to 128-mult (MPAD).
  static const int CIN [12] = {259,515,512,512,576,576,768,768,768,960,960,896};
  static const int KPAD[12] = {320,576,512,512,576,576,768,768,768,960,960,896};
  static const int COUT[12] = {515,512,512,576,576,768,768,768,960,960,896,1};
  static const int MPAD[12] = {640,512,512,640,640,768,768,768,1024,1024,896,1};

  size_t woff[13]; woff[0] = 0;
  for (int l = 0; l < 12; ++l) woff[l + 1] = woff[l] + (size_t)MPAD[l] * KPAD[l];

  char* ws = (char*)d_ws;
  u16* Wall = (u16*)ws;
  size_t off = (woff[12] * 2 + 255) & ~(size_t)255;
  u16* x0  = (u16*)(ws + off); off += (size_t)NPTS * 320 * 2;
  u16* XGA = (u16*)(ws + off); off += (size_t)4 * NPTS * 960 * 2;
  u16* XGB = (u16*)(ws + off);
  // total ws use ~77 MB

  float* out_sdf  = (float*)d_out;           // [4096]
  float* out_grad = out_sdf + NPTS;          // [4096][3]
  float* out_con  = out_sdf + NPTS + NPTS*3; // [4096][259]

  build_x0<<<dim3(NPTS), dim3(256), 0, stream>>>(
      (const float*)d_in[0], (const float*)d_in[1], x0, out_con);

  AllDesc ad;
  for (int l = 0; l < 12; ++l) {
    ad.d[l].v = (const float*)d_in[2 + 3 * l];
    ad.d[l].g = (const float*)d_in[3 + 3 * l];
    ad.d[l].Cin = CIN[l]; ad.d[l].Kpad = KPAD[l];
    ad.d[l].Cout = COUT[l]; ad.d[l].Mpad = MPAD[l];
    ad.d[l].woff = (int)woff[l];
  }
  wnorm_kernel<<<dim3(1024, 12), dim3(256), 0, stream>>>(ad, Wall);

  // layer 0 (first): x0 -> XGA (out stride = KPAD[1]); grid 32 x 5 -> 160 blocks
  {
    const int ny = MPAD[0] / 128;
    layer_mfma<true><<<dim3((NPTS / 128) * ny), dim3(256), 0, stream>>>(
        Wall + woff[0], (const float*)d_in[4], x0, XGA, KPAD[0], COUT[0], KPAD[1], ny);
  }

  // layers 1..10: ping-pong; tile rows = 4 streams x 32 points
  u16* bufs[2] = {XGA, XGB};
  for (int l = 1; l <= 10; ++l) {
    u16* Xi = bufs[(l + 1) & 1];
    u16* Xo = bufs[l & 1];
    const int ny = MPAD[l] / 128;
    layer_mfma<false><<<dim3((NPTS / 32) * ny), dim3(256), 0, stream>>>(
        Wall + woff[l], (const float*)d_in[4 + 3 * l], Xi, Xo,
        KPAD[l], COUT[l], KPAD[l + 1], ny);
  }

  // final: layer 10 wrote XGA (stride 896)
  final_c10<<<dim3(NPTS / 4), dim3(256), 0, stream>>>(
      Wall + woff[11], (const float*)d_in[37], XGA, out_sdf, out_grad);
}

// Round 4
// 654.770 us; speedup vs baseline: 4.1125x; 1.6179x over previous
//
#include <hip/hip_runtime.h>
#include <hip/hip_bf16.h>

// Network_70918499991665: 12-layer implicit-map extractor, fwd + analytic grad.
// Round 3: kill register-spill scratch traffic -> global_load_lds (w=16) staging,
// linear LDS + XOR swizzle (involution k16 ^ (row&7)), m97-style 2-barrier K-loop.

#define NPTS 4096

typedef unsigned short u16;
typedef unsigned int   u32;
typedef __attribute__((ext_vector_type(8))) __bf16 bf16x8;
typedef __attribute__((ext_vector_type(4))) float  f32x4;

#define GLD_LDS16(g, l) __builtin_amdgcn_global_load_lds(                  \
    (const __attribute__((address_space(1))) void*)(g),                   \
    (__attribute__((address_space(3))) void*)(l), 16, 0, 0)

__device__ __forceinline__ float bf2f(u16 h) {
  return __uint_as_float(((u32)h) << 16);
}
__device__ __forceinline__ u16 f2bf(float f) {
  u32 u = __float_as_uint(f);
  u += 0x7fff + ((u >> 16) & 1);   // RNE
  return (u16)(u >> 16);
}

// softplus(100x)/100 and sigmoid(100x), numerically stable
__device__ __forceinline__ void act_sp_sg(float pre, float& sp, float& sg) {
  float z = 100.f * pre;
  float e = __expf(-fabsf(z));
  float r = 1.f / (1.f + e);
  float l = log1pf(e) * 0.01f;
  if (z >= 0.f) { sg = r;       sp = pre + l; }
  else          { sg = 1.f - r; sp = l; }
}

// ---------------- weight norm: w[o] = g[o]*v[o]/||v[o]||, store bf16, pad zeros
struct LayerDesc { const float* v; const float* g; int Cin, Kpad, Cout, Mpad, woff; };
struct AllDesc { LayerDesc d[12]; };

__global__ __launch_bounds__(256)
void wnorm_kernel(AllDesc ad, u16* __restrict__ Wall) {
  const LayerDesc L = ad.d[blockIdx.y];
  const int o = blockIdx.x;
  if (o >= L.Mpad) return;
  u16* wrow = Wall + (size_t)L.woff + (size_t)o * L.Kpad;
  const int t = threadIdx.x;
  if (o >= L.Cout) {                       // zero pad rows
    for (int i = t; i < L.Kpad; i += 256) wrow[i] = 0;
    return;
  }
  const float* vrow = L.v + (size_t)o * L.Cin;
  float ss = 0.f;
  for (int i = t; i < L.Cin; i += 256) { float x = vrow[i]; ss += x * x; }
#pragma unroll
  for (int off = 32; off > 0; off >>= 1) ss += __shfl_down(ss, off);
  __shared__ float red[4];
  if ((t & 63) == 0) red[t >> 6] = ss;
  __syncthreads();
  const float scale = L.g[o] / sqrtf(red[0] + red[1] + red[2] + red[3]);
  for (int i = t; i < L.Kpad; i += 256)
    wrow[i] = (i < L.Cin) ? f2bf(vrow[i] * scale) : (u16)0;
}

// ---------------- build x0 [n][320] bf16 (pad 0) + input_con output (f32)
__global__ __launch_bounds__(256)
void build_x0(const float* __restrict__ inp, const float* __restrict__ lat,
              u16* __restrict__ x0, float* __restrict__ con) {
  const int n = blockIdx.x;
  for (int i = threadIdx.x; i < 320; i += 256) {
    float v = (i < 3) ? inp[n * 3 + i] : ((i < 259) ? lat[i - 3] : 0.f);
    x0[(size_t)n * 320 + i] = f2bf(v);
    if (i < 259) con[(size_t)n * 259 + i] = v;
  }
}

// bijective XCD swizzle (grid % 8 == 0 by construction), m-major chunks
__device__ __forceinline__ void xcd_decode(int nb, int ny, int& bx, int& by) {
  const int q = nb >> 3;
  const int wg = (blockIdx.x & 7) * q + (blockIdx.x >> 3);
  bx = wg / ny;
  by = wg - bx * ny;
}

// ---------------- fused MFMA layer, 128x128 tile, BK=64, 4 waves
// LDS tiles are LINEAR [128][64] u16 with XOR swizzle: slot (row, x) holds
// k-chunk x ^ (row&7)  (16B chunks). global_load_lds writes base+lane*16;
// the per-lane GLOBAL address carries the inverse permutation.
template<bool FIRST>
__global__ __launch_bounds__(256)
void layer_mfma(const u16* __restrict__ W, const float* __restrict__ bias,
                const u16* __restrict__ Xin, u16* __restrict__ Xout,
                int Kpad, int Cout, int Cstr, int ny) {
  __shared__ __align__(16) u16 smem[18432];    // 36,864 B
  u16* As = smem;                              // [128][64] linear+swz
  u16* Bs = smem + 8192;                       // [128][64] linear+swz
  const int t = threadIdx.x;
  const int wid = t >> 6, lane = t & 63;
  const int wr = wid >> 1, wc = wid & 1;
  const int lcol = lane & 15;
  const int hi = lane >> 4;
  const int lrow4 = hi * 4;

  int bx, by;
  xcd_decode(gridDim.x, ny, bx, by);
  const int n0 = bx * (FIRST ? 128 : 32);
  const int m0 = by * 128;

  f32x4 acc[4][4];
#pragma unroll
  for (int m = 0; m < 4; ++m)
#pragma unroll
    for (int n = 0; n < 4; ++n) acc[m][n] = (f32x4){0.f, 0.f, 0.f, 0.f};

  // staging geometry: wave stages rows wid*32..wid*32+31 of A and B, 4 instrs
  // of 8 rows (1KB) each. lane -> (row_in_group = lane>>3, chunk = lane&7);
  // global chunk fetched = (lane&7) ^ (lane>>3)  [inverse swizzle].
  const int ldiv = lane >> 3;
  const int kswz = ((lane & 7) ^ ldiv) * 8;            // u16 units
  const u16* gA = FIRST
      ? Xin + (size_t)(n0 + wid * 32 + ldiv) * Kpad + kswz
      : Xin + ((size_t)wid * NPTS + n0 + ldiv) * Kpad + kswz;
  const u16* gB = W + (size_t)(m0 + wid * 32 + ldiv) * Kpad + kswz;

  const int ksteps = Kpad >> 6;
  for (int ks = 0; ks < ksteps; ++ks) {
    const int k0 = ks << 6;
#pragma unroll
    for (int i = 0; i < 4; ++i) {
      GLD_LDS16(gA + (size_t)i * 8 * Kpad + k0, As + (wid * 32 + i * 8) * 64);
      GLD_LDS16(gB + (size_t)i * 8 * Kpad + k0, Bs + (wid * 32 + i * 8) * 64);
    }
    __syncthreads();   // vmcnt(0) drain -> LDS tiles ready
#pragma unroll
    for (int kk = 0; kk < 2; ++kk) {
      bf16x8 af[4], bfr[4];
#pragma unroll
      for (int m = 0; m < 4; ++m) {
        const int row = wr * 64 + m * 16 + lcol;
        af[m] = *reinterpret_cast<const bf16x8*>(
            &As[row * 64 + (((kk * 4 + hi) ^ (row & 7)) * 8)]);
      }
#pragma unroll
      for (int n = 0; n < 4; ++n) {
        const int row = wc * 64 + n * 16 + lcol;
        bfr[n] = *reinterpret_cast<const bf16x8*>(
            &Bs[row * 64 + (((kk * 4 + hi) ^ (row & 7)) * 8)]);
      }
#pragma unroll
      for (int m = 0; m < 4; ++m)
#pragma unroll
        for (int n = 0; n < 4; ++n)
          acc[m][n] = __builtin_amdgcn_mfma_f32_16x16x32_bf16(af[m], bfr[n], acc[m][n], 0, 0, 0);
    }
    __syncthreads();   // readers done before next stage overwrites
  }

  if constexpr (!FIRST) {
    u16* tile = smem;                 // [64][144] u16 (18,432 B)
    u16* sgL  = smem + 64 * 144;      // [32][136] bf16 (8,704 B)

    if (wr == 0) {     // stream-0 rows (0..31): sg -> LDS(bf16), acc -> softplus
#pragma unroll
      for (int m = 0; m < 2; ++m)
#pragma unroll
        for (int n = 0; n < 4; ++n) {
          const int colL = wc * 64 + n * 16 + lcol;
          const int col = m0 + colL;
          const float bcol = (col < Cout) ? bias[col] : 0.f;
#pragma unroll
          for (int i = 0; i < 4; ++i) {
            const int p = m * 16 + lrow4 + i;
            float sp = 0.f, sg = 0.f;
            if (col < Cout) act_sp_sg(acc[m][n][i] + bcol, sp, sg);
            sgL[p * 136 + colL] = f2bf(sg);
            acc[m][n][i] = sp;
          }
        }
    }
    __syncthreads();

    auto store_half = [&](int sbase) {
#pragma unroll
      for (int j = 0; j < 4; ++j) {
        const int c = j * 256 + t;
        const int row = c >> 4, colc = c & 15;
        const int colg = m0 + colc * 8;
        if (colg < Cstr) {
          const int s = sbase + (row >> 5), p = row & 31;
          *reinterpret_cast<uint4*>(
              &Xout[((size_t)s * NPTS + n0 + p) * Cstr + colg]) =
              *reinterpret_cast<const uint4*>(&tile[row * 144 + colc * 8]);
        }
      }
    };

    // half A: rows 0..63 = streams 0,1 (owned by wr==0 waves)
    if (wr == 0) {
#pragma unroll
      for (int m = 0; m < 4; ++m)
#pragma unroll
        for (int n = 0; n < 4; ++n) {
          const int colL = wc * 64 + n * 16 + lcol;
#pragma unroll
          for (int i = 0; i < 4; ++i) {
            const int row = m * 16 + lrow4 + i;   // 0..63
            const float v = (row < 32) ? acc[m][n][i]
                                       : bf2f(sgL[(row & 31) * 136 + colL]) * acc[m][n][i];
            tile[row * 144 + colL] = f2bf(v);
          }
        }
    }
    __syncthreads();
    store_half(0);
    __syncthreads();
    // half B: rows 64..127 = streams 2,3 (owned by wr==1 waves)
    if (wr == 1) {
#pragma unroll
      for (int m = 0; m < 4; ++m)
#pragma unroll
        for (int n = 0; n < 4; ++n) {
          const int colL = wc * 64 + n * 16 + lcol;
#pragma unroll
          for (int i = 0; i < 4; ++i) {
            const int row = m * 16 + lrow4 + i;   // tile row 0..63
            const float v = bf2f(sgL[(row & 31) * 136 + colL]) * acc[m][n][i];
            tile[row * 144 + colL] = f2bf(v);
          }
        }
    }
    __syncthreads();
    store_half(2);
  } else {
    u16* tile = smem;                 // [128][144] u16 = 36,864 B exactly
    float w0r[4], w1r[4], w2r[4], bcolr[4];
#pragma unroll
    for (int n = 0; n < 4; ++n) {
      const int col = m0 + wc * 64 + n * 16 + lcol;
      float b = 0.f, w0 = 0.f, w1 = 0.f, w2 = 0.f;
      if (col < Cout) {
        b  = bias[col];
        w0 = bf2f(W[(size_t)col * Kpad + 0]);
        w1 = bf2f(W[(size_t)col * Kpad + 1]);
        w2 = bf2f(W[(size_t)col * Kpad + 2]);
      }
      bcolr[n] = b; w0r[n] = w0; w1r[n] = w1; w2r[n] = w2;
    }
#pragma unroll
    for (int s = 0; s < 4; ++s) {
      if (s > 0) __syncthreads();
#pragma unroll
      for (int m = 0; m < 4; ++m)
#pragma unroll
        for (int n = 0; n < 4; ++n) {
          const int colL = wc * 64 + n * 16 + lcol;
          const bool ok = (m0 + colL) < Cout;
#pragma unroll
          for (int i = 0; i < 4; ++i) {
            const int row = wr * 64 + m * 16 + lrow4 + i;
            float v = 0.f;
            if (ok) {
              float sp, sg;
              act_sp_sg(acc[m][n][i] + bcolr[n], sp, sg);
              v = (s == 0) ? sp
                : (s == 1) ? sg * w0r[n]
                : (s == 2) ? sg * w1r[n]
                           : sg * w2r[n];
            }
            tile[row * 144 + colL] = f2bf(v);
          }
        }
      __syncthreads();
#pragma unroll
      for (int j = 0; j < 8; ++j) {
        const int c = j * 256 + t;
        const int row = c >> 4, colc = c & 15;
        const int colg = m0 + colc * 8;
        if (colg < Cstr) {
          *reinterpret_cast<uint4*>(
              &Xout[((size_t)s * NPTS + n0 + row) * Cstr + colg]) =
              *reinterpret_cast<const uint4*>(&tile[row * 144 + colc * 8]);
        }
      }
    }
  }
}

// ---------------- final 1-channel layer: out + out_grad
__global__ __launch_bounds__(256)
void final_c10(const u16* __restrict__ W10, const float* __restrict__ b10,
               const u16* __restrict__ Xin, float* __restrict__ out,
               float* __restrict__ outg) {
  const int lane = threadIdx.x & 63;
  const int n = blockIdx.x * 4 + (threadIdx.x >> 6);
  float a0 = 0, a1 = 0, a2 = 0, a3 = 0;
  for (int i = lane; i < 896; i += 64) {
    const float w = bf2f(W10[i]);
    a0 += w * bf2f(Xin[((size_t)0 * NPTS + n) * 896 + i]);
    a1 += w * bf2f(Xin[((size_t)1 * NPTS + n) * 896 + i]);
    a2 += w * bf2f(Xin[((size_t)2 * NPTS + n) * 896 + i]);
    a3 += w * bf2f(Xin[((size_t)3 * NPTS + n) * 896 + i]);
  }
#pragma unroll
  for (int off = 32; off > 0; off >>= 1) {
    a0 += __shfl_xor(a0, off); a1 += __shfl_xor(a1, off);
    a2 += __shfl_xor(a2, off); a3 += __shfl_xor(a3, off);
  }
  if (lane == 0) {
    out[n] = a0 + b10[0];
    outg[n * 3 + 0] = a1; outg[n * 3 + 1] = a2; outg[n * 3 + 2] = a3;
  }
}

extern "C" void kernel_launch(void* const* d_in, const int* in_sizes, int n_in,
                              void* d_out, int out_size, void* d_ws, size_t ws_size,
                              hipStream_t stream) {
  // K padded to 64-mult; Cout padded to 128-mult (MPAD).
  static const int CIN [12] = {259,515,512,512,576,576,768,768,768,960,960,896};
  static const int KPAD[12] = {320,576,512,512,576,576,768,768,768,960,960,896};
  static const int COUT[12] = {515,512,512,576,576,768,768,768,960,960,896,1};
  static const int MPAD[12] = {640,512,512,640,640,768,768,768,1024,1024,896,1};

  size_t woff[13]; woff[0] = 0;
  for (int l = 0; l < 12; ++l) woff[l + 1] = woff[l] + (size_t)MPAD[l] * KPAD[l];

  char* ws = (char*)d_ws;
  u16* Wall = (u16*)ws;
  size_t off = (woff[12] * 2 + 255) & ~(size_t)255;
  u16* x0  = (u16*)(ws + off); off += (size_t)NPTS * 320 * 2;
  u16* XGA = (u16*)(ws + off); off += (size_t)4 * NPTS * 960 * 2;
  u16* XGB = (u16*)(ws + off);
  // total ws use ~77 MB

  float* out_sdf  = (float*)d_out;           // [4096]
  float* out_grad = out_sdf + NPTS;          // [4096][3]
  float* out_con  = out_sdf + NPTS + NPTS*3; // [4096][259]

  build_x0<<<dim3(NPTS), dim3(256), 0, stream>>>(
      (const float*)d_in[0], (const float*)d_in[1], x0, out_con);

  AllDesc ad;
  for (int l = 0; l < 12; ++l) {
    ad.d[l].v = (const float*)d_in[2 + 3 * l];
    ad.d[l].g = (const float*)d_in[3 + 3 * l];
    ad.d[l].Cin = CIN[l]; ad.d[l].Kpad = KPAD[l];
    ad.d[l].Cout = COUT[l]; ad.d[l].Mpad = MPAD[l];
    ad.d[l].woff = (int)woff[l];
  }
  wnorm_kernel<<<dim3(1024, 12), dim3(256), 0, stream>>>(ad, Wall);

  // layer 0 (first): x0 -> XGA (out stride = KPAD[1]); grid 32 x 5 = 160 blocks
  {
    const int ny = MPAD[0] / 128;
    layer_mfma<true><<<dim3((NPTS / 128) * ny), dim3(256), 0, stream>>>(
        Wall + woff[0], (const float*)d_in[4], x0, XGA, KPAD[0], COUT[0], KPAD[1], ny);
  }

  // layers 1..10: ping-pong; tile rows = 4 streams x 32 points
  u16* bufs[2] = {XGA, XGB};
  for (int l = 1; l <= 10; ++l) {
    u16* Xi = bufs[(l + 1) & 1];
    u16* Xo = bufs[l & 1];
    const int ny = MPAD[l] / 128;
    layer_mfma<false><<<dim3((NPTS / 32) * ny), dim3(256), 0, stream>>>(
        Wall + woff[l], (const float*)d_in[4 + 3 * l], Xi, Xo,
        KPAD[l], COUT[l], KPAD[l + 1], ny);
  }

  // final: layer 10 wrote XGA (stride 896)
  final_c10<<<dim3(NPTS / 4), dim3(256), 0, stream>>>(
      Wall + woff[11], (const float*)d_in[37], XGA, out_sdf, out_grad);
}

// Round 5
// 448.852 us; speedup vs baseline: 5.9992x; 1.4588x over previous
//
#include <hip/hip_runtime.h>
#include <hip/hip_bf16.h>

// Network_70918499991665: 12-layer implicit-map extractor, fwd + analytic grad.
// Round 4: T3-minimum double-buffered prefetch K-loop — STAGE(t+1) issued before
// compute(t), one vmcnt(0)+barrier per step (was: stage -> drain -> compute, 2 barriers).

#define NPTS 4096

typedef unsigned short u16;
typedef unsigned int   u32;
typedef __attribute__((ext_vector_type(8))) __bf16 bf16x8;
typedef __attribute__((ext_vector_type(4))) float  f32x4;

#define GLD_LDS16(g, l) __builtin_amdgcn_global_load_lds(                  \
    (const __attribute__((address_space(1))) void*)(g),                   \
    (__attribute__((address_space(3))) void*)(l), 16, 0, 0)

__device__ __forceinline__ float bf2f(u16 h) {
  return __uint_as_float(((u32)h) << 16);
}
__device__ __forceinline__ u16 f2bf(float f) {
  u32 u = __float_as_uint(f);
  u += 0x7fff + ((u >> 16) & 1);   // RNE
  return (u16)(u >> 16);
}

// softplus(100x)/100 and sigmoid(100x), numerically stable
__device__ __forceinline__ void act_sp_sg(float pre, float& sp, float& sg) {
  float z = 100.f * pre;
  float e = __expf(-fabsf(z));
  float r = 1.f / (1.f + e);
  float l = __logf(1.f + e) * 0.01f;
  if (z >= 0.f) { sg = r;       sp = pre + l; }
  else          { sg = 1.f - r; sp = l; }
}

// ---------------- weight norm: w[o] = g[o]*v[o]/||v[o]||, store bf16, pad zeros
struct LayerDesc { const float* v; const float* g; int Cin, Kpad, Cout, Mpad, woff; };
struct AllDesc { LayerDesc d[12]; };

__global__ __launch_bounds__(256)
void wnorm_kernel(AllDesc ad, u16* __restrict__ Wall) {
  const LayerDesc L = ad.d[blockIdx.y];
  const int o = blockIdx.x;
  if (o >= L.Mpad) return;
  u16* wrow = Wall + (size_t)L.woff + (size_t)o * L.Kpad;
  const int t = threadIdx.x;
  if (o >= L.Cout) {                       // zero pad rows
    for (int i = t; i < L.Kpad; i += 256) wrow[i] = 0;
    return;
  }
  const float* vrow = L.v + (size_t)o * L.Cin;
  float ss = 0.f;
  for (int i = t; i < L.Cin; i += 256) { float x = vrow[i]; ss += x * x; }
#pragma unroll
  for (int off = 32; off > 0; off >>= 1) ss += __shfl_down(ss, off);
  __shared__ float red[4];
  if ((t & 63) == 0) red[t >> 6] = ss;
  __syncthreads();
  const float scale = L.g[o] / sqrtf(red[0] + red[1] + red[2] + red[3]);
  for (int i = t; i < L.Kpad; i += 256)
    wrow[i] = (i < L.Cin) ? f2bf(vrow[i] * scale) : (u16)0;
}

// ---------------- build x0 [n][320] bf16 (pad 0) + input_con output (f32)
__global__ __launch_bounds__(256)
void build_x0(const float* __restrict__ inp, const float* __restrict__ lat,
              u16* __restrict__ x0, float* __restrict__ con) {
  const int n = blockIdx.x;
  for (int i = threadIdx.x; i < 320; i += 256) {
    float v = (i < 3) ? inp[n * 3 + i] : ((i < 259) ? lat[i - 3] : 0.f);
    x0[(size_t)n * 320 + i] = f2bf(v);
    if (i < 259) con[(size_t)n * 259 + i] = v;
  }
}

// bijective XCD swizzle (grid % 8 == 0 by construction), m-major chunks
__device__ __forceinline__ void xcd_decode(int nb, int ny, int& bx, int& by) {
  const int q = nb >> 3;
  const int wg = (blockIdx.x & 7) * q + (blockIdx.x >> 3);
  bx = wg / ny;
  by = wg - bx * ny;
}

// ---------------- fused MFMA layer, 128x128 tile, BK=64, 4 waves,
// double-buffered global_load_lds prefetch (depth 1), XOR-swizzled LDS.
// LDS tile layout: LINEAR [128][64] u16; slot (row, x16) holds k-chunk
// x16 ^ (row&7); inverse permutation applied on the per-lane GLOBAL address.
template<bool FIRST>
__global__ __launch_bounds__(256)
void layer_mfma(const u16* __restrict__ W, const float* __restrict__ bias,
                const u16* __restrict__ Xin, u16* __restrict__ Xout,
                int Kpad, int Cout, int Cstr, int ny) {
  __shared__ __align__(16) u16 smem[32768];    // 64 KiB: 2 x (A 16KB + B 16KB)
  const int t = threadIdx.x;
  const int wid = t >> 6, lane = t & 63;
  const int wr = wid >> 1, wc = wid & 1;
  const int lcol = lane & 15;
  const int hi = lane >> 4;
  const int lrow4 = hi * 4;

  int bx, by;
  xcd_decode(gridDim.x, ny, bx, by);
  const int n0 = bx * (FIRST ? 128 : 32);
  const int m0 = by * 128;

  f32x4 acc[4][4];
#pragma unroll
  for (int m = 0; m < 4; ++m)
#pragma unroll
    for (int n = 0; n < 4; ++n) acc[m][n] = (f32x4){0.f, 0.f, 0.f, 0.f};

  // staging geometry: wave stages rows wid*32..+31 of A and B, 4 instrs of
  // 8 rows (1KB) each. lane -> (row = lane>>3, chunk = (lane&7) ^ (lane>>3)).
  const int ldiv = lane >> 3;
  const int kswz = ((lane & 7) ^ ldiv) * 8;            // u16 units
  const u16* gA = FIRST
      ? Xin + (size_t)(n0 + wid * 32 + ldiv) * Kpad + kswz
      : Xin + ((size_t)wid * NPTS + n0 + ldiv) * Kpad + kswz;
  const u16* gB = W + (size_t)(m0 + wid * 32 + ldiv) * Kpad + kswz;

  auto stage = [&](int ks, int bufoff) {
    const int k0 = ks << 6;
#pragma unroll
    for (int i = 0; i < 4; ++i) {
      GLD_LDS16(gA + (size_t)i * 8 * Kpad + k0,
                smem + bufoff + (wid * 32 + i * 8) * 64);
      GLD_LDS16(gB + (size_t)i * 8 * Kpad + k0,
                smem + bufoff + 8192 + (wid * 32 + i * 8) * 64);
    }
  };

  const int ksteps = Kpad >> 6;
  stage(0, 0);
  __syncthreads();                     // drain prologue stage (vmcnt(0))
  int cur = 0;
  for (int ks = 0; ks < ksteps; ++ks) {
    if (ks + 1 < ksteps) stage(ks + 1, (cur ^ 1) << 14);   // issue next tile
    const u16* As = smem + (cur << 14);
    const u16* Bs = As + 8192;
#pragma unroll
    for (int kk = 0; kk < 2; ++kk) {
      bf16x8 af[4], bfr[4];
#pragma unroll
      for (int m = 0; m < 4; ++m) {
        const int row = wr * 64 + m * 16 + lcol;
        af[m] = *reinterpret_cast<const bf16x8*>(
            &As[row * 64 + (((kk * 4 + hi) ^ (row & 7)) * 8)]);
      }
#pragma unroll
      for (int n = 0; n < 4; ++n) {
        const int row = wc * 64 + n * 16 + lcol;
        bfr[n] = *reinterpret_cast<const bf16x8*>(
            &Bs[row * 64 + (((kk * 4 + hi) ^ (row & 7)) * 8)]);
      }
#pragma unroll
      for (int m = 0; m < 4; ++m)
#pragma unroll
        for (int n = 0; n < 4; ++n)
          acc[m][n] = __builtin_amdgcn_mfma_f32_16x16x32_bf16(af[m], bfr[n], acc[m][n], 0, 0, 0);
    }
    __syncthreads();   // vmcnt(0): next tile landed; readers done w/ cur buffer
    cur ^= 1;
  }

  if constexpr (!FIRST) {
    u16* tile = smem;                 // [64][144] u16 (18,432 B)
    u16* sgL  = smem + 64 * 144;      // [32][136] bf16 (8,704 B)

    if (wr == 0) {     // stream-0 rows (0..31): sg -> LDS(bf16), acc -> softplus
#pragma unroll
      for (int m = 0; m < 2; ++m)
#pragma unroll
        for (int n = 0; n < 4; ++n) {
          const int colL = wc * 64 + n * 16 + lcol;
          const int col = m0 + colL;
          const float bcol = (col < Cout) ? bias[col] : 0.f;
#pragma unroll
          for (int i = 0; i < 4; ++i) {
            const int p = m * 16 + lrow4 + i;
            float sp = 0.f, sg = 0.f;
            if (col < Cout) act_sp_sg(acc[m][n][i] + bcol, sp, sg);
            sgL[p * 136 + colL] = f2bf(sg);
            acc[m][n][i] = sp;
          }
        }
    }
    __syncthreads();

    auto store_half = [&](int sbase) {
#pragma unroll
      for (int j = 0; j < 4; ++j) {
        const int c = j * 256 + t;
        const int row = c >> 4, colc = c & 15;
        const int colg = m0 + colc * 8;
        if (colg < Cstr) {
          const int s = sbase + (row >> 5), p = row & 31;
          *reinterpret_cast<uint4*>(
              &Xout[((size_t)s * NPTS + n0 + p) * Cstr + colg]) =
              *reinterpret_cast<const uint4*>(&tile[row * 144 + colc * 8]);
        }
      }
    };

    // half A: rows 0..63 = streams 0,1 (owned by wr==0 waves)
    if (wr == 0) {
#pragma unroll
      for (int m = 0; m < 4; ++m)
#pragma unroll
        for (int n = 0; n < 4; ++n) {
          const int colL = wc * 64 + n * 16 + lcol;
#pragma unroll
          for (int i = 0; i < 4; ++i) {
            const int row = m * 16 + lrow4 + i;   // 0..63
            const float v = (row < 32) ? acc[m][n][i]
                                       : bf2f(sgL[(row & 31) * 136 + colL]) * acc[m][n][i];
            tile[row * 144 + colL] = f2bf(v);
          }
        }
    }
    __syncthreads();
    store_half(0);
    __syncthreads();
    // half B: rows 64..127 = streams 2,3 (owned by wr==1 waves)
    if (wr == 1) {
#pragma unroll
      for (int m = 0; m < 4; ++m)
#pragma unroll
        for (int n = 0; n < 4; ++n) {
          const int colL = wc * 64 + n * 16 + lcol;
#pragma unroll
          for (int i = 0; i < 4; ++i) {
            const int row = m * 16 + lrow4 + i;   // tile row 0..63
            const float v = bf2f(sgL[(row & 31) * 136 + colL]) * acc[m][n][i];
            tile[row * 144 + colL] = f2bf(v);
          }
        }
    }
    __syncthreads();
    store_half(2);
  } else {
    u16* tile = smem;                 // [128][144] u16 = 36,864 B
    float w0r[4], w1r[4], w2r[4], bcolr[4];
#pragma unroll
    for (int n = 0; n < 4; ++n) {
      const int col = m0 + wc * 64 + n * 16 + lcol;
      float b = 0.f, w0 = 0.f, w1 = 0.f, w2 = 0.f;
      if (col < Cout) {
        b  = bias[col];
        w0 = bf2f(W[(size_t)col * Kpad + 0]);
        w1 = bf2f(W[(size_t)col * Kpad + 1]);
        w2 = bf2f(W[(size_t)col * Kpad + 2]);
      }
      bcolr[n] = b; w0r[n] = w0; w1r[n] = w1; w2r[n] = w2;
    }
#pragma unroll
    for (int s = 0; s < 4; ++s) {
      if (s > 0) __syncthreads();
#pragma unroll
      for (int m = 0; m < 4; ++m)
#pragma unroll
        for (int n = 0; n < 4; ++n) {
          const int colL = wc * 64 + n * 16 + lcol;
          const bool ok = (m0 + colL) < Cout;
#pragma unroll
          for (int i = 0; i < 4; ++i) {
            const int row = wr * 64 + m * 16 + lrow4 + i;
            float v = 0.f;
            if (ok) {
              float sp, sg;
              act_sp_sg(acc[m][n][i] + bcolr[n], sp, sg);
              v = (s == 0) ? sp
                : (s == 1) ? sg * w0r[n]
                : (s == 2) ? sg * w1r[n]
                           : sg * w2r[n];
            }
            tile[row * 144 + colL] = f2bf(v);
          }
        }
      __syncthreads();
#pragma unroll
      for (int j = 0; j < 8; ++j) {
        const int c = j * 256 + t;
        const int row = c >> 4, colc = c & 15;
        const int colg = m0 + colc * 8;
        if (colg < Cstr) {
          *reinterpret_cast<uint4*>(
              &Xout[((size_t)s * NPTS + n0 + row) * Cstr + colg]) =
              *reinterpret_cast<const uint4*>(&tile[row * 144 + colc * 8]);
        }
      }
    }
  }
}

// ---------------- final 1-channel layer: out + out_grad
__global__ __launch_bounds__(256)
void final_c10(const u16* __restrict__ W10, const float* __restrict__ b10,
               const u16* __restrict__ Xin, float* __restrict__ out,
               float* __restrict__ outg) {
  const int lane = threadIdx.x & 63;
  const int n = blockIdx.x * 4 + (threadIdx.x >> 6);
  float a0 = 0, a1 = 0, a2 = 0, a3 = 0;
  for (int i = lane; i < 896; i += 64) {
    const float w = bf2f(W10[i]);
    a0 += w * bf2f(Xin[((size_t)0 * NPTS + n) * 896 + i]);
    a1 += w * bf2f(Xin[((size_t)1 * NPTS + n) * 896 + i]);
    a2 += w * bf2f(Xin[((size_t)2 * NPTS + n) * 896 + i]);
    a3 += w * bf2f(Xin[((size_t)3 * NPTS + n) * 896 + i]);
  }
#pragma unroll
  for (int off = 32; off > 0; off >>= 1) {
    a0 += __shfl_xor(a0, off); a1 += __shfl_xor(a1, off);
    a2 += __shfl_xor(a2, off); a3 += __shfl_xor(a3, off);
  }
  if (lane == 0) {
    out[n] = a0 + b10[0];
    outg[n * 3 + 0] = a1; outg[n * 3 + 1] = a2; outg[n * 3 + 2] = a3;
  }
}

extern "C" void kernel_launch(void* const* d_in, const int* in_sizes, int n_in,
                              void* d_out, int out_size, void* d_ws, size_t ws_size,
                              hipStream_t stream) {
  // K padded to 64-mult; Cout padded to 128-mult (MPAD).
  static const int CIN [12] = {259,515,512,512,576,576,768,768,768,960,960,896};
  static const int KPAD[12] = {320,576,512,512,576,576,768,768,768,960,960,896};
  static const int COUT[12] = {515,512,512,576,576,768,768,768,960,960,896,1};
  static const int MPAD[12] = {640,512,512,640,640,768,768,768,1024,1024,896,1};

  size_t woff[13]; woff[0] = 0;
  for (int l = 0; l < 12; ++l) woff[l + 1] = woff[l] + (size_t)MPAD[l] * KPAD[l];

  char* ws = (char*)d_ws;
  u16* Wall = (u16*)ws;
  size_t off = (woff[12] * 2 + 255) & ~(size_t)255;
  u16* x0  = (u16*)(ws + off); off += (size_t)NPTS * 320 * 2;
  u16* XGA = (u16*)(ws + off); off += (size_t)4 * NPTS * 960 * 2;
  u16* XGB = (u16*)(ws + off);
  // total ws use ~77 MB

  float* out_sdf  = (float*)d_out;           // [4096]
  float* out_grad = out_sdf + NPTS;          // [4096][3]
  float* out_con  = out_sdf + NPTS + NPTS*3; // [4096][259]

  build_x0<<<dim3(NPTS), dim3(256), 0, stream>>>(
      (const float*)d_in[0], (const float*)d_in[1], x0, out_con);

  AllDesc ad;
  for (int l = 0; l < 12; ++l) {
    ad.d[l].v = (const float*)d_in[2 + 3 * l];
    ad.d[l].g = (const float*)d_in[3 + 3 * l];
    ad.d[l].Cin = CIN[l]; ad.d[l].Kpad = KPAD[l];
    ad.d[l].Cout = COUT[l]; ad.d[l].Mpad = MPAD[l];
    ad.d[l].woff = (int)woff[l];
  }
  wnorm_kernel<<<dim3(1024, 12), dim3(256), 0, stream>>>(ad, Wall);

  // layer 0 (first): x0 -> XGA (out stride = KPAD[1]); grid 32 x 5 = 160 blocks
  {
    const int ny = MPAD[0] / 128;
    layer_mfma<true><<<dim3((NPTS / 128) * ny), dim3(256), 0, stream>>>(
        Wall + woff[0], (const float*)d_in[4], x0, XGA, KPAD[0], COUT[0], KPAD[1], ny);
  }

  // layers 1..10: ping-pong; tile rows = 4 streams x 32 points
  u16* bufs[2] = {XGA, XGB};
  for (int l = 1; l <= 10; ++l) {
    u16* Xi = bufs[(l + 1) & 1];
    u16* Xo = bufs[l & 1];
    const int ny = MPAD[l] / 128;
    layer_mfma<false><<<dim3((NPTS / 32) * ny), dim3(256), 0, stream>>>(
        Wall + woff[l], (const float*)d_in[4 + 3 * l], Xi, Xo,
        KPAD[l], COUT[l], KPAD[l + 1], ny);
  }

  // final: layer 10 wrote XGA (stride 896)
  final_c10<<<dim3(NPTS / 4), dim3(256), 0, stream>>>(
      Wall + woff[11], (const float*)d_in[37], XGA, out_sdf, out_grad);
}

// Round 6
// 442.299 us; speedup vs baseline: 6.0881x; 1.0148x over previous
//
#include <hip/hip_runtime.h>
#include <hip/hip_bf16.h>

// Network_70918499991665: 12-layer implicit-map extractor, fwd + analytic grad.
// Round 5: T4 counted-vmcnt pipeline — s_waitcnt vmcnt(8) + raw s_barrier keeps
// next-tile prefetch in flight across the barrier (was: __syncthreads -> vmcnt(0)
// drain of the just-issued prefetch). Buffer overwrite guarded by lgkmcnt(0)+barrier.

#define NPTS 4096

typedef unsigned short u16;
typedef unsigned int   u32;
typedef __attribute__((ext_vector_type(8))) __bf16 bf16x8;
typedef __attribute__((ext_vector_type(4))) float  f32x4;

#define GLD_LDS16(g, l) __builtin_amdgcn_global_load_lds(                  \
    (const __attribute__((address_space(1))) void*)(g),                   \
    (__attribute__((address_space(3))) void*)(l), 16, 0, 0)

__device__ __forceinline__ float bf2f(u16 h) {
  return __uint_as_float(((u32)h) << 16);
}
__device__ __forceinline__ u16 f2bf(float f) {
  u32 u = __float_as_uint(f);
  u += 0x7fff + ((u >> 16) & 1);   // RNE
  return (u16)(u >> 16);
}

// softplus(100x)/100 and sigmoid(100x), numerically stable
__device__ __forceinline__ void act_sp_sg(float pre, float& sp, float& sg) {
  float z = 100.f * pre;
  float e = __expf(-fabsf(z));
  float r = 1.f / (1.f + e);
  float l = __logf(1.f + e) * 0.01f;
  if (z >= 0.f) { sg = r;       sp = pre + l; }
  else          { sg = 1.f - r; sp = l; }
}

// ---------------- weight norm: w[o] = g[o]*v[o]/||v[o]||, store bf16, pad zeros
struct LayerDesc { const float* v; const float* g; int Cin, Kpad, Cout, Mpad, woff; };
struct AllDesc { LayerDesc d[12]; };

__global__ __launch_bounds__(256)
void wnorm_kernel(AllDesc ad, u16* __restrict__ Wall) {
  const LayerDesc L = ad.d[blockIdx.y];
  const int o = blockIdx.x;
  if (o >= L.Mpad) return;
  u16* wrow = Wall + (size_t)L.woff + (size_t)o * L.Kpad;
  const int t = threadIdx.x;
  if (o >= L.Cout) {                       // zero pad rows
    for (int i = t; i < L.Kpad; i += 256) wrow[i] = 0;
    return;
  }
  const float* vrow = L.v + (size_t)o * L.Cin;
  float ss = 0.f;
  for (int i = t; i < L.Cin; i += 256) { float x = vrow[i]; ss += x * x; }
#pragma unroll
  for (int off = 32; off > 0; off >>= 1) ss += __shfl_down(ss, off);
  __shared__ float red[4];
  if ((t & 63) == 0) red[t >> 6] = ss;
  __syncthreads();
  const float scale = L.g[o] / sqrtf(red[0] + red[1] + red[2] + red[3]);
  for (int i = t; i < L.Kpad; i += 256)
    wrow[i] = (i < L.Cin) ? f2bf(vrow[i] * scale) : (u16)0;
}

// ---------------- build x0 [n][320] bf16 (pad 0) + input_con output (f32)
__global__ __launch_bounds__(256)
void build_x0(const float* __restrict__ inp, const float* __restrict__ lat,
              u16* __restrict__ x0, float* __restrict__ con) {
  const int n = blockIdx.x;
  for (int i = threadIdx.x; i < 320; i += 256) {
    float v = (i < 3) ? inp[n * 3 + i] : ((i < 259) ? lat[i - 3] : 0.f);
    x0[(size_t)n * 320 + i] = f2bf(v);
    if (i < 259) con[(size_t)n * 259 + i] = v;
  }
}

// bijective XCD swizzle (grid % 8 == 0 by construction), m-major chunks
__device__ __forceinline__ void xcd_decode(int nb, int ny, int& bx, int& by) {
  const int q = nb >> 3;
  const int wg = (blockIdx.x & 7) * q + (blockIdx.x >> 3);
  bx = wg / ny;
  by = wg - bx * ny;
}

// ---------------- fused MFMA layer, 128x128 tile, BK=64, 4 waves,
// double-buffered global_load_lds prefetch with COUNTED vmcnt (T4):
//   top:  vmcnt(8) [stage(t) landed; stage(t+1) stays in flight] + barrier
//   body: ds_read + MFMA on buf[t&1]
//   end:  lgkmcnt(0) [own LDS reads drained] + barrier; stage(t+2) -> buf[t&1]
// LDS tile layout: LINEAR [128][64] u16; slot (row, x16) holds k-chunk
// x16 ^ (row&7); inverse permutation applied on the per-lane GLOBAL address.
template<bool FIRST>
__global__ __launch_bounds__(256)
void layer_mfma(const u16* __restrict__ W, const float* __restrict__ bias,
                const u16* __restrict__ Xin, u16* __restrict__ Xout,
                int Kpad, int Cout, int Cstr, int ny) {
  __shared__ __align__(16) u16 smem[32768];    // 64 KiB: 2 x (A 16KB + B 16KB)
  const int t = threadIdx.x;
  const int wid = t >> 6, lane = t & 63;
  const int wr = wid >> 1, wc = wid & 1;
  const int lcol = lane & 15;
  const int hi = lane >> 4;
  const int lrow4 = hi * 4;

  int bx, by;
  xcd_decode(gridDim.x, ny, bx, by);
  const int n0 = bx * (FIRST ? 128 : 32);
  const int m0 = by * 128;

  f32x4 acc[4][4];
#pragma unroll
  for (int m = 0; m < 4; ++m)
#pragma unroll
    for (int n = 0; n < 4; ++n) acc[m][n] = (f32x4){0.f, 0.f, 0.f, 0.f};

  // staging geometry: wave stages rows wid*32..+31 of A and B, 4 instrs of
  // 8 rows (1KB) each. lane -> (row = lane>>3, chunk = (lane&7) ^ (lane>>3)).
  const int ldiv = lane >> 3;
  const int kswz = ((lane & 7) ^ ldiv) * 8;            // u16 units
  const u16* gA = FIRST
      ? Xin + (size_t)(n0 + wid * 32 + ldiv) * Kpad + kswz
      : Xin + ((size_t)wid * NPTS + n0 + ldiv) * Kpad + kswz;
  const u16* gB = W + (size_t)(m0 + wid * 32 + ldiv) * Kpad + kswz;

  auto stage = [&](int ks, int bufbase) {   // bufbase in u16 units
    const int k0 = ks << 6;
#pragma unroll
    for (int i = 0; i < 4; ++i) {
      GLD_LDS16(gA + (size_t)i * 8 * Kpad + k0,
                smem + bufbase + (wid * 32 + i * 8) * 64);
      GLD_LDS16(gB + (size_t)i * 8 * Kpad + k0,
                smem + bufbase + 8192 + (wid * 32 + i * 8) * 64);
    }
  };

  const int ksteps = Kpad >> 6;              // >= 5 for all layers
  stage(0, 0);
  stage(1, 16384);
  int cur = 0;
  for (int ks = 0; ks < ksteps; ++ks) {
    if (ks + 1 < ksteps) {
      asm volatile("s_waitcnt vmcnt(8)" ::: "memory");   // stage(ks) landed
    } else {
      asm volatile("s_waitcnt vmcnt(0)" ::: "memory");   // last tile: drain all
    }
    __builtin_amdgcn_s_barrier();
    const u16* As = smem + cur * 16384;
    const u16* Bs = As + 8192;
#pragma unroll
    for (int kk = 0; kk < 2; ++kk) {
      bf16x8 af[4], bfr[4];
#pragma unroll
      for (int m = 0; m < 4; ++m) {
        const int row = wr * 64 + m * 16 + lcol;
        af[m] = *reinterpret_cast<const bf16x8*>(
            &As[row * 64 + (((kk * 4 + hi) ^ (row & 7)) * 8)]);
      }
#pragma unroll
      for (int n = 0; n < 4; ++n) {
        const int row = wc * 64 + n * 16 + lcol;
        bfr[n] = *reinterpret_cast<const bf16x8*>(
            &Bs[row * 64 + (((kk * 4 + hi) ^ (row & 7)) * 8)]);
      }
#pragma unroll
      for (int m = 0; m < 4; ++m)
#pragma unroll
        for (int n = 0; n < 4; ++n)
          acc[m][n] = __builtin_amdgcn_mfma_f32_16x16x32_bf16(af[m], bfr[n], acc[m][n], 0, 0, 0);
    }
    asm volatile("s_waitcnt lgkmcnt(0)" ::: "memory");   // own ds_reads drained
    __builtin_amdgcn_s_barrier();                        // all waves done w/ cur
    if (ks + 2 < ksteps) stage(ks + 2, cur * 16384);     // overwrite cur buffer
    cur ^= 1;
  }

  if constexpr (!FIRST) {
    u16* tile = smem;                 // [64][144] u16 (18,432 B)
    u16* sgL  = smem + 64 * 144;      // [32][136] bf16 (8,704 B)

    if (wr == 0) {     // stream-0 rows (0..31): sg -> LDS(bf16), acc -> softplus
#pragma unroll
      for (int m = 0; m < 2; ++m)
#pragma unroll
        for (int n = 0; n < 4; ++n) {
          const int colL = wc * 64 + n * 16 + lcol;
          const int col = m0 + colL;
          const float bcol = (col < Cout) ? bias[col] : 0.f;
#pragma unroll
          for (int i = 0; i < 4; ++i) {
            const int p = m * 16 + lrow4 + i;
            float sp = 0.f, sg = 0.f;
            if (col < Cout) act_sp_sg(acc[m][n][i] + bcol, sp, sg);
            sgL[p * 136 + colL] = f2bf(sg);
            acc[m][n][i] = sp;
          }
        }
    }
    __syncthreads();

    auto store_half = [&](int sbase) {
#pragma unroll
      for (int j = 0; j < 4; ++j) {
        const int c = j * 256 + t;
        const int row = c >> 4, colc = c & 15;
        const int colg = m0 + colc * 8;
        if (colg < Cstr) {
          const int s = sbase + (row >> 5), p = row & 31;
          *reinterpret_cast<uint4*>(
              &Xout[((size_t)s * NPTS + n0 + p) * Cstr + colg]) =
              *reinterpret_cast<const uint4*>(&tile[row * 144 + colc * 8]);
        }
      }
    };

    // half A: rows 0..63 = streams 0,1 (owned by wr==0 waves)
    if (wr == 0) {
#pragma unroll
      for (int m = 0; m < 4; ++m)
#pragma unroll
        for (int n = 0; n < 4; ++n) {
          const int colL = wc * 64 + n * 16 + lcol;
#pragma unroll
          for (int i = 0; i < 4; ++i) {
            const int row = m * 16 + lrow4 + i;   // 0..63
            const float v = (row < 32) ? acc[m][n][i]
                                       : bf2f(sgL[(row & 31) * 136 + colL]) * acc[m][n][i];
            tile[row * 144 + colL] = f2bf(v);
          }
        }
    }
    __syncthreads();
    store_half(0);
    __syncthreads();
    // half B: rows 64..127 = streams 2,3 (owned by wr==1 waves)
    if (wr == 1) {
#pragma unroll
      for (int m = 0; m < 4; ++m)
#pragma unroll
        for (int n = 0; n < 4; ++n) {
          const int colL = wc * 64 + n * 16 + lcol;
#pragma unroll
          for (int i = 0; i < 4; ++i) {
            const int row = m * 16 + lrow4 + i;   // tile row 0..63
            const float v = bf2f(sgL[(row & 31) * 136 + colL]) * acc[m][n][i];
            tile[row * 144 + colL] = f2bf(v);
          }
        }
    }
    __syncthreads();
    store_half(2);
  } else {
    u16* tile = smem;                 // [128][144] u16 = 36,864 B
    float w0r[4], w1r[4], w2r[4], bcolr[4];
#pragma unroll
    for (int n = 0; n < 4; ++n) {
      const int col = m0 + wc * 64 + n * 16 + lcol;
      float b = 0.f, w0 = 0.f, w1 = 0.f, w2 = 0.f;
      if (col < Cout) {
        b  = bias[col];
        w0 = bf2f(W[(size_t)col * Kpad + 0]);
        w1 = bf2f(W[(size_t)col * Kpad + 1]);
        w2 = bf2f(W[(size_t)col * Kpad + 2]);
      }
      bcolr[n] = b; w0r[n] = w0; w1r[n] = w1; w2r[n] = w2;
    }
#pragma unroll
    for (int s = 0; s < 4; ++s) {
      if (s > 0) __syncthreads();
#pragma unroll
      for (int m = 0; m < 4; ++m)
#pragma unroll
        for (int n = 0; n < 4; ++n) {
          const int colL = wc * 64 + n * 16 + lcol;
          const bool ok = (m0 + colL) < Cout;
#pragma unroll
          for (int i = 0; i < 4; ++i) {
            const int row = wr * 64 + m * 16 + lrow4 + i;
            float v = 0.f;
            if (ok) {
              float sp, sg;
              act_sp_sg(acc[m][n][i] + bcolr[n], sp, sg);
              v = (s == 0) ? sp
                : (s == 1) ? sg * w0r[n]
                : (s == 2) ? sg * w1r[n]
                           : sg * w2r[n];
            }
            tile[row * 144 + colL] = f2bf(v);
          }
        }
      __syncthreads();
#pragma unroll
      for (int j = 0; j < 8; ++j) {
        const int c = j * 256 + t;
        const int row = c >> 4, colc = c & 15;
        const int colg = m0 + colc * 8;
        if (colg < Cstr) {
          *reinterpret_cast<uint4*>(
              &Xout[((size_t)s * NPTS + n0 + row) * Cstr + colg]) =
              *reinterpret_cast<const uint4*>(&tile[row * 144 + colc * 8]);
        }
      }
    }
  }
}

// ---------------- final 1-channel layer: out + out_grad
__global__ __launch_bounds__(256)
void final_c10(const u16* __restrict__ W10, const float* __restrict__ b10,
               const u16* __restrict__ Xin, float* __restrict__ out,
               float* __restrict__ outg) {
  const int lane = threadIdx.x & 63;
  const int n = blockIdx.x * 4 + (threadIdx.x >> 6);
  float a0 = 0, a1 = 0, a2 = 0, a3 = 0;
  for (int i = lane; i < 896; i += 64) {
    const float w = bf2f(W10[i]);
    a0 += w * bf2f(Xin[((size_t)0 * NPTS + n) * 896 + i]);
    a1 += w * bf2f(Xin[((size_t)1 * NPTS + n) * 896 + i]);
    a2 += w * bf2f(Xin[((size_t)2 * NPTS + n) * 896 + i]);
    a3 += w * bf2f(Xin[((size_t)3 * NPTS + n) * 896 + i]);
  }
#pragma unroll
  for (int off = 32; off > 0; off >>= 1) {
    a0 += __shfl_xor(a0, off); a1 += __shfl_xor(a1, off);
    a2 += __shfl_xor(a2, off); a3 += __shfl_xor(a3, off);
  }
  if (lane == 0) {
    out[n] = a0 + b10[0];
    outg[n * 3 + 0] = a1; outg[n * 3 + 1] = a2; outg[n * 3 + 2] = a3;
  }
}

extern "C" void kernel_launch(void* const* d_in, const int* in_sizes, int n_in,
                              void* d_out, int out_size, void* d_ws, size_t ws_size,
                              hipStream_t stream) {
  // K padded to 64-mult; Cout padded to 128-mult (MPAD).
  static const int CIN [12] = {259,515,512,512,576,576,768,768,768,960,960,896};
  static const int KPAD[12] = {320,576,512,512,576,576,768,768,768,960,960,896};
  static const int COUT[12] = {515,512,512,576,576,768,768,768,960,960,896,1};
  static const int MPAD[12] = {640,512,512,640,640,768,768,768,1024,1024,896,1};

  size_t woff[13]; woff[0] = 0;
  for (int l = 0; l < 12; ++l) woff[l + 1] = woff[l] + (size_t)MPAD[l] * KPAD[l];

  char* ws = (char*)d_ws;
  u16* Wall = (u16*)ws;
  size_t off = (woff[12] * 2 + 255) & ~(size_t)255;
  u16* x0  = (u16*)(ws + off); off += (size_t)NPTS * 320 * 2;
  u16* XGA = (u16*)(ws + off); off += (size_t)4 * NPTS * 960 * 2;
  u16* XGB = (u16*)(ws + off);
  // total ws use ~77 MB

  float* out_sdf  = (float*)d_out;           // [4096]
  float* out_grad = out_sdf + NPTS;          // [4096][3]
  float* out_con  = out_sdf + NPTS + NPTS*3; // [4096][259]

  build_x0<<<dim3(NPTS), dim3(256), 0, stream>>>(
      (const float*)d_in[0], (const float*)d_in[1], x0, out_con);

  AllDesc ad;
  for (int l = 0; l < 12; ++l) {
    ad.d[l].v = (const float*)d_in[2 + 3 * l];
    ad.d[l].g = (const float*)d_in[3 + 3 * l];
    ad.d[l].Cin = CIN[l]; ad.d[l].Kpad = KPAD[l];
    ad.d[l].Cout = COUT[l]; ad.d[l].Mpad = MPAD[l];
    ad.d[l].woff = (int)woff[l];
  }
  wnorm_kernel<<<dim3(1024, 12), dim3(256), 0, stream>>>(ad, Wall);

  // layer 0 (first): x0 -> XGA (out stride = KPAD[1]); grid 32 x 5 = 160 blocks
  {
    const int ny = MPAD[0] / 128;
    layer_mfma<true><<<dim3((NPTS / 128) * ny), dim3(256), 0, stream>>>(
        Wall + woff[0], (const float*)d_in[4], x0, XGA, KPAD[0], COUT[0], KPAD[1], ny);
  }

  // layers 1..10: ping-pong; tile rows = 4 streams x 32 points
  u16* bufs[2] = {XGA, XGB};
  for (int l = 1; l <= 10; ++l) {
    u16* Xi = bufs[(l + 1) & 1];
    u16* Xo = bufs[l & 1];
    const int ny = MPAD[l] / 128;
    layer_mfma<false><<<dim3((NPTS / 32) * ny), dim3(256), 0, stream>>>(
        Wall + woff[l], (const float*)d_in[4 + 3 * l], Xi, Xo,
        KPAD[l], COUT[l], KPAD[l + 1], ny);
  }

  // final: layer 10 wrote XGA (stride 896)
  final_c10<<<dim3(NPTS / 4), dim3(256), 0, stream>>>(
      Wall + woff[11], (const float*)d_in[37], XGA, out_sdf, out_grad);
}

// Round 7
// 412.561 us; speedup vs baseline: 6.5269x; 1.0721x over previous
//
#include <hip/hip_runtime.h>
#include <hip/hip_bf16.h>

// Network_70918499991665: 12-layer implicit-map extractor, fwd + analytic grad.
// Round 6: BK 64->32, dbuf LDS 64KB->32KB (36.9KB block total) => 4 blocks/CU
// (was 2). Mechanism: latency-bound loop needs TLP; LDS was the occupancy cap.
// BK=32 swizzle chunk' = k ^ (row&3) is bank-even (8x16B slots, 32B/bank floor).

#define NPTS 4096

typedef unsigned short u16;
typedef unsigned int   u32;
typedef __attribute__((ext_vector_type(8))) __bf16 bf16x8;
typedef __attribute__((ext_vector_type(4))) float  f32x4;

#define GLD_LDS16(g, l) __builtin_amdgcn_global_load_lds(                  \
    (const __attribute__((address_space(1))) void*)(g),                   \
    (__attribute__((address_space(3))) void*)(l), 16, 0, 0)

__device__ __forceinline__ float bf2f(u16 h) {
  return __uint_as_float(((u32)h) << 16);
}
__device__ __forceinline__ u16 f2bf(float f) {
  u32 u = __float_as_uint(f);
  u += 0x7fff + ((u >> 16) & 1);   // RNE
  return (u16)(u >> 16);
}

// softplus(100x)/100 and sigmoid(100x), numerically stable
__device__ __forceinline__ void act_sp_sg(float pre, float& sp, float& sg) {
  float z = 100.f * pre;
  float e = __expf(-fabsf(z));
  float r = 1.f / (1.f + e);
  float l = __logf(1.f + e) * 0.01f;
  if (z >= 0.f) { sg = r;       sp = pre + l; }
  else          { sg = 1.f - r; sp = l; }
}

// ---------------- weight norm: w[o] = g[o]*v[o]/||v[o]||, store bf16, pad zeros
struct LayerDesc { const float* v; const float* g; int Cin, Kpad, Cout, Mpad, woff; };
struct AllDesc { LayerDesc d[12]; };

__global__ __launch_bounds__(256)
void wnorm_kernel(AllDesc ad, u16* __restrict__ Wall) {
  const LayerDesc L = ad.d[blockIdx.y];
  const int o = blockIdx.x;
  if (o >= L.Mpad) return;
  u16* wrow = Wall + (size_t)L.woff + (size_t)o * L.Kpad;
  const int t = threadIdx.x;
  if (o >= L.Cout) {                       // zero pad rows
    for (int i = t; i < L.Kpad; i += 256) wrow[i] = 0;
    return;
  }
  const float* vrow = L.v + (size_t)o * L.Cin;
  float ss = 0.f;
  for (int i = t; i < L.Cin; i += 256) { float x = vrow[i]; ss += x * x; }
#pragma unroll
  for (int off = 32; off > 0; off >>= 1) ss += __shfl_down(ss, off);
  __shared__ float red[4];
  if ((t & 63) == 0) red[t >> 6] = ss;
  __syncthreads();
  const float scale = L.g[o] / sqrtf(red[0] + red[1] + red[2] + red[3]);
  for (int i = t; i < L.Kpad; i += 256)
    wrow[i] = (i < L.Cin) ? f2bf(vrow[i] * scale) : (u16)0;
}

// ---------------- build x0 [n][320] bf16 (pad 0) + input_con output (f32)
__global__ __launch_bounds__(256)
void build_x0(const float* __restrict__ inp, const float* __restrict__ lat,
              u16* __restrict__ x0, float* __restrict__ con) {
  const int n = blockIdx.x;
  for (int i = threadIdx.x; i < 320; i += 256) {
    float v = (i < 3) ? inp[n * 3 + i] : ((i < 259) ? lat[i - 3] : 0.f);
    x0[(size_t)n * 320 + i] = f2bf(v);
    if (i < 259) con[(size_t)n * 259 + i] = v;
  }
}

// bijective XCD swizzle (grid % 8 == 0 by construction), m-major chunks
__device__ __forceinline__ void xcd_decode(int nb, int ny, int& bx, int& by) {
  const int q = nb >> 3;
  const int wg = (blockIdx.x & 7) * q + (blockIdx.x >> 3);
  bx = wg / ny;
  by = wg - bx * ny;
}

// ---------------- fused MFMA layer, 128x128 tile, BK=32, 4 waves,
// double-buffered global_load_lds prefetch, counted vmcnt(4).
// LDS tile: LINEAR [128 rows][32 u16]; slot (row, c16) holds k-chunk
// c16 ^ (row&3); inverse permutation on the per-lane GLOBAL address.
template<bool FIRST>
__global__ __launch_bounds__(256, 4)
void layer_mfma(const u16* __restrict__ W, const float* __restrict__ bias,
                const u16* __restrict__ Xin, u16* __restrict__ Xout,
                int Kpad, int Cout, int Cstr, int ny) {
  __shared__ __align__(16) u16 smem[18432];   // 36,864 B; loop uses first 32 KB
  const int t = threadIdx.x;
  const int wid = t >> 6, lane = t & 63;
  const int wr = wid >> 1, wc = wid & 1;
  const int lcol = lane & 15;
  const int hi = lane >> 4;                   // k-chunk 0..3 (8 bf16 each)
  const int lrow4 = hi * 4;

  int bx, by;
  xcd_decode(gridDim.x, ny, bx, by);
  const int n0 = bx * (FIRST ? 128 : 32);
  const int m0 = by * 128;

  f32x4 acc[4][4];
#pragma unroll
  for (int m = 0; m < 4; ++m)
#pragma unroll
    for (int n = 0; n < 4; ++n) acc[m][n] = (f32x4){0.f, 0.f, 0.f, 0.f};

  // staging: wave stages rows wid*32..+31 of A and B, 2 instrs of 16 rows each.
  // lane -> (row = lane>>2, chunk = (lane&3) ^ ((lane>>2)&3))  [inverse swizzle]
  const int ldiv = lane >> 2;
  const int kswz = ((lane & 3) ^ (ldiv & 3)) * 8;      // u16 units
  const u16* gA = FIRST
      ? Xin + (size_t)(n0 + wid * 32 + ldiv) * Kpad + kswz
      : Xin + ((size_t)wid * NPTS + n0 + ldiv) * Kpad + kswz;
  const u16* gB = W + (size_t)(m0 + wid * 32 + ldiv) * Kpad + kswz;

  auto stage = [&](int ks, int bufbase) {   // bufbase in u16 units
    const int k0 = ks << 5;
#pragma unroll
    for (int i = 0; i < 2; ++i) {
      GLD_LDS16(gA + (size_t)i * 16 * Kpad + k0,
                smem + bufbase + (wid * 32 + i * 16) * 32);
      GLD_LDS16(gB + (size_t)i * 16 * Kpad + k0,
                smem + bufbase + 4096 + (wid * 32 + i * 16) * 32);
    }
  };

  const int ksteps = Kpad >> 5;              // >= 10 for all layers
  stage(0, 0);
  stage(1, 8192);
  int cur = 0;
  for (int ks = 0; ks < ksteps; ++ks) {
    if (ks + 1 < ksteps) {
      asm volatile("s_waitcnt vmcnt(4)" ::: "memory");   // stage(ks) landed
    } else {
      asm volatile("s_waitcnt vmcnt(0)" ::: "memory");   // last tile: drain all
    }
    __builtin_amdgcn_s_barrier();
    const u16* As = smem + cur * 8192;
    const u16* Bs = As + 4096;
    bf16x8 af[4], bfr[4];
#pragma unroll
    for (int m = 0; m < 4; ++m) {
      const int row = wr * 64 + m * 16 + lcol;
      af[m] = *reinterpret_cast<const bf16x8*>(
          &As[row * 32 + ((hi ^ (lcol & 3)) * 8)]);
    }
#pragma unroll
    for (int n = 0; n < 4; ++n) {
      const int row = wc * 64 + n * 16 + lcol;
      bfr[n] = *reinterpret_cast<const bf16x8*>(
          &Bs[row * 32 + ((hi ^ (lcol & 3)) * 8)]);
    }
#pragma unroll
    for (int m = 0; m < 4; ++m)
#pragma unroll
      for (int n = 0; n < 4; ++n)
        acc[m][n] = __builtin_amdgcn_mfma_f32_16x16x32_bf16(af[m], bfr[n], acc[m][n], 0, 0, 0);
    asm volatile("s_waitcnt lgkmcnt(0)" ::: "memory");   // own ds_reads drained
    __builtin_amdgcn_s_barrier();                        // all waves done w/ cur
    if (ks + 2 < ksteps) stage(ks + 2, cur * 8192);      // overwrite cur buffer
    cur ^= 1;
  }

  if constexpr (!FIRST) {
    u16* tile = smem;                 // [64][144] u16 (18,432 B)
    u16* sgL  = smem + 64 * 144;      // [32][136] bf16 (8,704 B)

    if (wr == 0) {     // stream-0 rows (0..31): sg -> LDS(bf16), acc -> softplus
#pragma unroll
      for (int m = 0; m < 2; ++m)
#pragma unroll
        for (int n = 0; n < 4; ++n) {
          const int colL = wc * 64 + n * 16 + lcol;
          const int col = m0 + colL;
          const float bcol = (col < Cout) ? bias[col] : 0.f;
#pragma unroll
          for (int i = 0; i < 4; ++i) {
            const int p = m * 16 + lrow4 + i;
            float sp = 0.f, sg = 0.f;
            if (col < Cout) act_sp_sg(acc[m][n][i] + bcol, sp, sg);
            sgL[p * 136 + colL] = f2bf(sg);
            acc[m][n][i] = sp;
          }
        }
    }
    __syncthreads();

    auto store_half = [&](int sbase) {
#pragma unroll
      for (int j = 0; j < 4; ++j) {
        const int c = j * 256 + t;
        const int row = c >> 4, colc = c & 15;
        const int colg = m0 + colc * 8;
        if (colg < Cstr) {
          const int s = sbase + (row >> 5), p = row & 31;
          *reinterpret_cast<uint4*>(
              &Xout[((size_t)s * NPTS + n0 + p) * Cstr + colg]) =
              *reinterpret_cast<const uint4*>(&tile[row * 144 + colc * 8]);
        }
      }
    };

    // half A: rows 0..63 = streams 0,1 (owned by wr==0 waves)
    if (wr == 0) {
#pragma unroll
      for (int m = 0; m < 4; ++m)
#pragma unroll
        for (int n = 0; n < 4; ++n) {
          const int colL = wc * 64 + n * 16 + lcol;
#pragma unroll
          for (int i = 0; i < 4; ++i) {
            const int row = m * 16 + lrow4 + i;   // 0..63
            const float v = (row < 32) ? acc[m][n][i]
                                       : bf2f(sgL[(row & 31) * 136 + colL]) * acc[m][n][i];
            tile[row * 144 + colL] = f2bf(v);
          }
        }
    }
    __syncthreads();
    store_half(0);
    __syncthreads();
    // half B: rows 64..127 = streams 2,3 (owned by wr==1 waves)
    if (wr == 1) {
#pragma unroll
      for (int m = 0; m < 4; ++m)
#pragma unroll
        for (int n = 0; n < 4; ++n) {
          const int colL = wc * 64 + n * 16 + lcol;
#pragma unroll
          for (int i = 0; i < 4; ++i) {
            const int row = m * 16 + lrow4 + i;   // tile row 0..63
            const float v = bf2f(sgL[(row & 31) * 136 + colL]) * acc[m][n][i];
            tile[row * 144 + colL] = f2bf(v);
          }
        }
    }
    __syncthreads();
    store_half(2);
  } else {
    u16* tile = smem;                 // [128][144] u16 = 36,864 B
    float w0r[4], w1r[4], w2r[4], bcolr[4];
#pragma unroll
    for (int n = 0; n < 4; ++n) {
      const int col = m0 + wc * 64 + n * 16 + lcol;
      float b = 0.f, w0 = 0.f, w1 = 0.f, w2 = 0.f;
      if (col < Cout) {
        b  = bias[col];
        w0 = bf2f(W[(size_t)col * Kpad + 0]);
        w1 = bf2f(W[(size_t)col * Kpad + 1]);
        w2 = bf2f(W[(size_t)col * Kpad + 2]);
      }
      bcolr[n] = b; w0r[n] = w0; w1r[n] = w1; w2r[n] = w2;
    }
#pragma unroll
    for (int s = 0; s < 4; ++s) {
      if (s > 0) __syncthreads();
#pragma unroll
      for (int m = 0; m < 4; ++m)
#pragma unroll
        for (int n = 0; n < 4; ++n) {
          const int colL = wc * 64 + n * 16 + lcol;
          const bool ok = (m0 + colL) < Cout;
#pragma unroll
          for (int i = 0; i < 4; ++i) {
            const int row = wr * 64 + m * 16 + lrow4 + i;
            float v = 0.f;
            if (ok) {
              float sp, sg;
              act_sp_sg(acc[m][n][i] + bcolr[n], sp, sg);
              v = (s == 0) ? sp
                : (s == 1) ? sg * w0r[n]
                : (s == 2) ? sg * w1r[n]
                           : sg * w2r[n];
            }
            tile[row * 144 + colL] = f2bf(v);
          }
        }
      __syncthreads();
#pragma unroll
      for (int j = 0; j < 8; ++j) {
        const int c = j * 256 + t;
        const int row = c >> 4, colc = c & 15;
        const int colg = m0 + colc * 8;
        if (colg < Cstr) {
          *reinterpret_cast<uint4*>(
              &Xout[((size_t)s * NPTS + n0 + row) * Cstr + colg]) =
              *reinterpret_cast<const uint4*>(&tile[row * 144 + colc * 8]);
        }
      }
    }
  }
}

// ---------------- final 1-channel layer: out + out_grad
__global__ __launch_bounds__(256)
void final_c10(const u16* __restrict__ W10, const float* __restrict__ b10,
               const u16* __restrict__ Xin, float* __restrict__ out,
               float* __restrict__ outg) {
  const int lane = threadIdx.x & 63;
  const int n = blockIdx.x * 4 + (threadIdx.x >> 6);
  float a0 = 0, a1 = 0, a2 = 0, a3 = 0;
  for (int i = lane; i < 896; i += 64) {
    const float w = bf2f(W10[i]);
    a0 += w * bf2f(Xin[((size_t)0 * NPTS + n) * 896 + i]);
    a1 += w * bf2f(Xin[((size_t)1 * NPTS + n) * 896 + i]);
    a2 += w * bf2f(Xin[((size_t)2 * NPTS + n) * 896 + i]);
    a3 += w * bf2f(Xin[((size_t)3 * NPTS + n) * 896 + i]);
  }
#pragma unroll
  for (int off = 32; off > 0; off >>= 1) {
    a0 += __shfl_xor(a0, off); a1 += __shfl_xor(a1, off);
    a2 += __shfl_xor(a2, off); a3 += __shfl_xor(a3, off);
  }
  if (lane == 0) {
    out[n] = a0 + b10[0];
    outg[n * 3 + 0] = a1; outg[n * 3 + 1] = a2; outg[n * 3 + 2] = a3;
  }
}

extern "C" void kernel_launch(void* const* d_in, const int* in_sizes, int n_in,
                              void* d_out, int out_size, void* d_ws, size_t ws_size,
                              hipStream_t stream) {
  // K padded to 32-mult (all are 64-mult too); Cout padded to 128-mult (MPAD).
  static const int CIN [12] = {259,515,512,512,576,576,768,768,768,960,960,896};
  static const int KPAD[12] = {320,576,512,512,576,576,768,768,768,960,960,896};
  static const int COUT[12] = {515,512,512,576,576,768,768,768,960,960,896,1};
  static const int MPAD[12] = {640,512,512,640,640,768,768,768,1024,1024,896,1};

  size_t woff[13]; woff[0] = 0;
  for (int l = 0; l < 12; ++l) woff[l + 1] = woff[l] + (size_t)MPAD[l] * KPAD[l];

  char* ws = (char*)d_ws;
  u16* Wall = (u16*)ws;
  size_t off = (woff[12] * 2 + 255) & ~(size_t)255;
  u16* x0  = (u16*)(ws + off); off += (size_t)NPTS * 320 * 2;
  u16* XGA = (u16*)(ws + off); off += (size_t)4 * NPTS * 960 * 2;
  u16* XGB = (u16*)(ws + off);
  // total ws use ~77 MB

  float* out_sdf  = (float*)d_out;           // [4096]
  float* out_grad = out_sdf + NPTS;          // [4096][3]
  float* out_con  = out_sdf + NPTS + NPTS*3; // [4096][259]

  build_x0<<<dim3(NPTS), dim3(256), 0, stream>>>(
      (const float*)d_in[0], (const float*)d_in[1], x0, out_con);

  AllDesc ad;
  for (int l = 0; l < 12; ++l) {
    ad.d[l].v = (const float*)d_in[2 + 3 * l];
    ad.d[l].g = (const float*)d_in[3 + 3 * l];
    ad.d[l].Cin = CIN[l]; ad.d[l].Kpad = KPAD[l];
    ad.d[l].Cout = COUT[l]; ad.d[l].Mpad = MPAD[l];
    ad.d[l].woff = (int)woff[l];
  }
  wnorm_kernel<<<dim3(1024, 12), dim3(256), 0, stream>>>(ad, Wall);

  // layer 0 (first): x0 -> XGA (out stride = KPAD[1]); grid 32 x 5 = 160 blocks
  {
    const int ny = MPAD[0] / 128;
    layer_mfma<true><<<dim3((NPTS / 128) * ny), dim3(256), 0, stream>>>(
        Wall + woff[0], (const float*)d_in[4], x0, XGA, KPAD[0], COUT[0], KPAD[1], ny);
  }

  // layers 1..10: ping-pong; tile rows = 4 streams x 32 points
  u16* bufs[2] = {XGA, XGB};
  for (int l = 1; l <= 10; ++l) {
    u16* Xi = bufs[(l + 1) & 1];
    u16* Xo = bufs[l & 1];
    const int ny = MPAD[l] / 128;
    layer_mfma<false><<<dim3((NPTS / 32) * ny), dim3(256), 0, stream>>>(
        Wall + woff[l], (const float*)d_in[4 + 3 * l], Xi, Xo,
        KPAD[l], COUT[l], KPAD[l + 1], ny);
  }

  // final: layer 10 wrote XGA (stride 896)
  final_c10<<<dim3(NPTS / 4), dim3(256), 0, stream>>>(
      Wall + woff[11], (const float*)d_in[37], XGA, out_sdf, out_grad);
}